// Round 3
// baseline (6115.659 us; speedup 1.0000x reference)
//
#include <hip/hip_runtime.h>
#include <math.h>

#define N_NODES 100000
#define N_EDGES 1600000
#define D_IN 512
#define D_HID 256
#define D_OUT 40

// ---------------------------------------------------------------------------
// Threefry-2x32, 20 rounds, key = (0, 42)  (jax.random.key(42))
// Returns both output words.
// ---------------------------------------------------------------------------
static __device__ __forceinline__ void threefry_0_42(unsigned x0, unsigned x1,
                                                     unsigned& o0, unsigned& o1) {
  const unsigned ks0 = 0u;
  const unsigned ks1 = 42u;
  const unsigned ks2 = 0u ^ 42u ^ 0x1BD11BDAu;
  x0 += ks0; x1 += ks1;
#define TF_R(r) { x0 += x1; x1 = (x1 << (r)) | (x1 >> (32 - (r))); x1 ^= x0; }
  TF_R(13) TF_R(15) TF_R(26) TF_R(6)
  x0 += ks1; x1 += ks2 + 1u;
  TF_R(17) TF_R(29) TF_R(16) TF_R(24)
  x0 += ks2; x1 += ks0 + 2u;
  TF_R(13) TF_R(15) TF_R(26) TF_R(6)
  x0 += ks0; x1 += ks1 + 3u;
  TF_R(17) TF_R(29) TF_R(16) TF_R(24)
  x0 += ks1; x1 += ks2 + 4u;
  TF_R(13) TF_R(15) TF_R(26) TF_R(6)
  x0 += ks2; x1 += ks0 + 5u;
#undef TF_R
  o0 = x0; o1 = x1;
}

// ---------------------------------------------------------------------------
// GEMM1: support1[100000,256] = x[100000,512] @ W1[512,256]   (f32)
// BM=64 BN=64 BK=32, 256 threads, 4x4 microtile per thread
// ---------------------------------------------------------------------------
__global__ __launch_bounds__(256) void gemm1_kernel(const float* __restrict__ x,
                                                    const float* __restrict__ W1,
                                                    float* __restrict__ out) {
  __shared__ float As[64][33];   // +1 pad: kills bank conflict on column reads
  __shared__ float Bs[32][64];

  const int tid = threadIdx.x;
  const int tx = tid % 16;           // col group (4 cols each)
  const int ty = tid / 16;           // row group (4 rows each)
  const int row0 = blockIdx.x * 64;
  const int col0 = blockIdx.y * 64;

  float acc[4][4] = {};

  for (int kt = 0; kt < D_IN; kt += 32) {
    // load A tile: 64 rows x 32 k
    {
      const int r  = tid / 4;          // 0..63
      const int kk = (tid % 4) * 8;    // 0,8,16,24
      const int grow = row0 + r;
      if (grow < N_NODES) {
        const float* src = x + (size_t)grow * D_IN + kt + kk;
        float4 v0 = *(const float4*)(src);
        float4 v1 = *(const float4*)(src + 4);
        As[r][kk + 0] = v0.x; As[r][kk + 1] = v0.y;
        As[r][kk + 2] = v0.z; As[r][kk + 3] = v0.w;
        As[r][kk + 4] = v1.x; As[r][kk + 5] = v1.y;
        As[r][kk + 6] = v1.z; As[r][kk + 7] = v1.w;
      } else {
        for (int q = 0; q < 8; ++q) As[r][kk + q] = 0.0f;
      }
    }
    // load B tile: 32 k x 64 cols
    {
      const int k = tid / 8;           // 0..31
      const int c = (tid % 8) * 8;     // 0..56
      const float* src = W1 + (size_t)(kt + k) * D_HID + col0 + c;
      float4 v0 = *(const float4*)(src);
      float4 v1 = *(const float4*)(src + 4);
      *(float4*)&Bs[k][c] = v0;
      *(float4*)&Bs[k][c + 4] = v1;
    }
    __syncthreads();

#pragma unroll
    for (int k = 0; k < 32; ++k) {
      const float a0 = As[ty * 4 + 0][k];
      const float a1 = As[ty * 4 + 1][k];
      const float a2 = As[ty * 4 + 2][k];
      const float a3 = As[ty * 4 + 3][k];
      const float4 b = *(const float4*)&Bs[k][tx * 4];
      acc[0][0] += a0 * b.x; acc[0][1] += a0 * b.y; acc[0][2] += a0 * b.z; acc[0][3] += a0 * b.w;
      acc[1][0] += a1 * b.x; acc[1][1] += a1 * b.y; acc[1][2] += a1 * b.z; acc[1][3] += a1 * b.w;
      acc[2][0] += a2 * b.x; acc[2][1] += a2 * b.y; acc[2][2] += a2 * b.z; acc[2][3] += a2 * b.w;
      acc[3][0] += a3 * b.x; acc[3][1] += a3 * b.y; acc[3][2] += a3 * b.z; acc[3][3] += a3 * b.w;
    }
    __syncthreads();
  }

#pragma unroll
  for (int i = 0; i < 4; ++i) {
    const int r = row0 + ty * 4 + i;
    if (r < N_NODES) {
      float4 v = make_float4(acc[i][0], acc[i][1], acc[i][2], acc[i][3]);
      *(float4*)&out[(size_t)r * D_HID + col0 + tx * 4] = v;
    }
  }
}

// ---------------------------------------------------------------------------
// SpMM1: acc[dst] += ew * support1[src]   (one wave per edge, 256 feats)
// ---------------------------------------------------------------------------
__global__ __launch_bounds__(256) void spmm1_kernel(const float* __restrict__ sup,
                                                    const int* __restrict__ esrc,
                                                    const int* __restrict__ edst,
                                                    const float* __restrict__ ew,
                                                    float* __restrict__ acc) {
  const int e = (blockIdx.x * 256 + threadIdx.x) >> 6;  // edge index (wave)
  const int lane = threadIdx.x & 63;
  if (e >= N_EDGES) return;
  const int s = esrc[e];
  const int d = edst[e];
  const float w = ew[e];
  const float4 v = *(const float4*)(sup + (size_t)s * D_HID + lane * 4);
  float* p = acc + (size_t)d * D_HID + lane * 4;
  atomicAdd(p + 0, v.x * w);
  atomicAdd(p + 1, v.y * w);
  atomicAdd(p + 2, v.z * w);
  atomicAdd(p + 3, v.w * w);
}

// ---------------------------------------------------------------------------
// bias + ReLU + dropout, in place.
// Dropout mask: JAX partitionable threefry (default since jax 0.5):
//   per element i (row-major flat):  (o0,o1) = threefry2x32((0,42), (i>>32, i&0xffffffff))
//   32-bit random word = o0 ^ o1   (prng.py sub-64-bit path XORs the two words);
//   keep iff word < 2^31  (uniform<0.5).
// ---------------------------------------------------------------------------
__global__ __launch_bounds__(256) void relu_dropout_kernel(float* __restrict__ h,
                                                           const float* __restrict__ b1) {
  const unsigned i = blockIdx.x * 256 + threadIdx.x;   // < 25,600,000 < 2^32
  unsigned o0, o1;
  threefry_0_42(0u, i, o0, o1);
  const unsigned word = o0 ^ o1;
  const int col = i & (D_HID - 1);
  float v = h[i] + b1[col];
  v = v > 0.0f ? v : 0.0f;
  h[i] = (word >> 31) ? 0.0f : v * 2.0f;
}

// ---------------------------------------------------------------------------
// GEMM2: support2[100000,40] = h[100000,256] @ W2[256,40]
// 32 rows per block, BK=64
// ---------------------------------------------------------------------------
__global__ __launch_bounds__(256) void gemm2_kernel(const float* __restrict__ h,
                                                    const float* __restrict__ W2,
                                                    float* __restrict__ out) {
  __shared__ float As[32][65];
  __shared__ float Ws[64][40];

  const int tid = threadIdx.x;
  const int row = tid / 8;        // 0..31
  const int cg  = tid % 8;        // col group: cols cg*5 .. cg*5+4
  const int row0 = blockIdx.x * 32;

  float acc[5] = {};

  for (int kt = 0; kt < D_HID; kt += 64) {
    // load A: 32 rows x 64 k
    {
      const int r = tid / 8;           // 0..31
      const int c = (tid % 8) * 8;     // 0..56
      const int grow = row0 + r;
      if (grow < N_NODES) {
        const float* src = h + (size_t)grow * D_HID + kt + c;
        float4 v0 = *(const float4*)(src);
        float4 v1 = *(const float4*)(src + 4);
        As[r][c + 0] = v0.x; As[r][c + 1] = v0.y; As[r][c + 2] = v0.z; As[r][c + 3] = v0.w;
        As[r][c + 4] = v1.x; As[r][c + 5] = v1.y; As[r][c + 6] = v1.z; As[r][c + 7] = v1.w;
      } else {
        for (int q = 0; q < 8; ++q) As[r][c + q] = 0.0f;
      }
    }
    // load W2 slab: 64 k x 40 cols
    {
      const int k = tid / 4;           // 0..63
      const int c = (tid % 4) * 10;    // 0,10,20,30
      const float* src = W2 + (size_t)(kt + k) * D_OUT + c;
      for (int q = 0; q < 10; ++q) Ws[k][c + q] = src[q];
    }
    __syncthreads();

#pragma unroll 8
    for (int k = 0; k < 64; ++k) {
      const float a = As[row][k];
#pragma unroll
      for (int j = 0; j < 5; ++j) acc[j] += a * Ws[k][cg * 5 + j];
    }
    __syncthreads();
  }

  const int grow = row0 + row;
  if (grow < N_NODES) {
#pragma unroll
    for (int j = 0; j < 5; ++j) out[(size_t)grow * D_OUT + cg * 5 + j] = acc[j];
  }
}

// ---------------------------------------------------------------------------
// SpMM2: acc[dst] += ew * support2[src]  (flat edge x feat)
// ---------------------------------------------------------------------------
__global__ __launch_bounds__(256) void spmm2_kernel(const float* __restrict__ sup,
                                                    const int* __restrict__ esrc,
                                                    const int* __restrict__ edst,
                                                    const float* __restrict__ ew,
                                                    float* __restrict__ acc) {
  const long long idx = (long long)blockIdx.x * 256 + threadIdx.x;
  if (idx >= (long long)N_EDGES * D_OUT) return;
  const int e = (int)(idx / D_OUT);
  const int f = (int)(idx % D_OUT);
  const float v = sup[(size_t)esrc[e] * D_OUT + f] * ew[e];
  atomicAdd(&acc[(size_t)edst[e] * D_OUT + f], v);
}

// ---------------------------------------------------------------------------
// bias + log_softmax over 40 classes, one wave per row
// ---------------------------------------------------------------------------
__global__ __launch_bounds__(256) void logsoftmax_kernel(const float* __restrict__ logits,
                                                         const float* __restrict__ b2,
                                                         float* __restrict__ out) {
  const int row = (blockIdx.x * 256 + threadIdx.x) >> 6;
  const int lane = threadIdx.x & 63;
  if (row >= N_NODES) return;
  float v = -INFINITY;
  if (lane < D_OUT) v = logits[(size_t)row * D_OUT + lane] + b2[lane];
  float m = v;
#pragma unroll
  for (int off = 32; off > 0; off >>= 1) m = fmaxf(m, __shfl_xor(m, off, 64));
  float e = (lane < D_OUT) ? expf(v - m) : 0.0f;
  float s = e;
#pragma unroll
  for (int off = 32; off > 0; off >>= 1) s += __shfl_xor(s, off, 64);
  if (lane < D_OUT) out[(size_t)row * D_OUT + lane] = v - m - logf(s);
}

// ---------------------------------------------------------------------------
extern "C" void kernel_launch(void* const* d_in, const int* in_sizes, int n_in,
                              void* d_out, int out_size, void* d_ws, size_t ws_size,
                              hipStream_t stream) {
  const float* x    = (const float*)d_in[0];
  const int*   esrc = (const int*)d_in[1];
  const int*   edst = (const int*)d_in[2];
  const float* ew   = (const float*)d_in[3];
  const float* W1   = (const float*)d_in[4];
  const float* b1   = (const float*)d_in[5];
  const float* W2   = (const float*)d_in[6];
  const float* b2   = (const float*)d_in[7];
  float* out = (float*)d_out;

  float* ws = (float*)d_ws;
  float* support1 = ws;                    // 25,600,000 floats
  float* hbuf     = ws + 25600000;         // 25,600,000 floats
  float* support2 = ws + 51200000;         //  4,000,000 floats
  float* logits   = ws + 55200000;         //  4,000,000 floats

  hipMemsetAsync(hbuf,   0, (size_t)25600000 * sizeof(float), stream);
  hipMemsetAsync(logits, 0, (size_t)4000000  * sizeof(float), stream);

  gemm1_kernel<<<dim3(1563, 4), 256, 0, stream>>>(x, W1, support1);
  spmm1_kernel<<<(N_EDGES + 3) / 4, 256, 0, stream>>>(support1, esrc, edst, ew, hbuf);
  relu_dropout_kernel<<<100000, 256, 0, stream>>>(hbuf, b1);
  gemm2_kernel<<<(N_NODES + 31) / 32, 256, 0, stream>>>(hbuf, W2, support2);
  spmm2_kernel<<<(N_EDGES * (long long)D_OUT + 255) / 256, 256, 0, stream>>>(support2, esrc, edst, ew, logits);
  logsoftmax_kernel<<<(N_NODES + 3) / 4, 256, 0, stream>>>(logits, b2, out);
}

// Round 4
// 1237.015 us; speedup vs baseline: 4.9439x; 4.9439x over previous
//
#include <hip/hip_runtime.h>
#include <math.h>

#define N_NODES 100000
#define N_EDGES 1600000
#define D_IN 512
#define D_HID 256
#define D_OUT 40

// ---------------------------------------------------------------------------
// Threefry-2x32, 20 rounds, key = (0, 42)  (jax.random.key(42))
// ---------------------------------------------------------------------------
static __device__ __forceinline__ void threefry_0_42(unsigned x0, unsigned x1,
                                                     unsigned& o0, unsigned& o1) {
  const unsigned ks0 = 0u;
  const unsigned ks1 = 42u;
  const unsigned ks2 = 0u ^ 42u ^ 0x1BD11BDAu;
  x0 += ks0; x1 += ks1;
#define TF_R(r) { x0 += x1; x1 = (x1 << (r)) | (x1 >> (32 - (r))); x1 ^= x0; }
  TF_R(13) TF_R(15) TF_R(26) TF_R(6)
  x0 += ks1; x1 += ks2 + 1u;
  TF_R(17) TF_R(29) TF_R(16) TF_R(24)
  x0 += ks2; x1 += ks0 + 2u;
  TF_R(13) TF_R(15) TF_R(26) TF_R(6)
  x0 += ks0; x1 += ks1 + 3u;
  TF_R(17) TF_R(29) TF_R(16) TF_R(24)
  x0 += ks1; x1 += ks2 + 4u;
  TF_R(13) TF_R(15) TF_R(26) TF_R(6)
  x0 += ks2; x1 += ks0 + 5u;
#undef TF_R
  o0 = x0; o1 = x1;
}

// ---------------------------------------------------------------------------
// CSR build: histogram of edge_dst
// ---------------------------------------------------------------------------
__global__ __launch_bounds__(256) void hist_kernel(const int* __restrict__ edst,
                                                   int* __restrict__ counts) {
  const int e = blockIdx.x * 256 + threadIdx.x;
  if (e < N_EDGES) atomicAdd(&counts[edst[e]], 1);
}

// One block, 256 threads: chunked exclusive scan of counts -> rowptr, cursor
__global__ __launch_bounds__(256) void scan_kernel(const int* __restrict__ counts,
                                                   int* __restrict__ rowptr,
                                                   int* __restrict__ cursor) {
  __shared__ int sums[256];
  const int t = threadIdx.x;
  const int chunk = (N_NODES + 255) / 256;           // 391
  const int beg = t * chunk;
  const int end = (beg + chunk < N_NODES) ? beg + chunk : N_NODES;
  int s = 0;
  for (int i = beg; i < end; ++i) s += counts[i];
  sums[t] = s;
  __syncthreads();
  // inclusive Hillis-Steele scan over thread totals
  for (int off = 1; off < 256; off <<= 1) {
    int tmp = (t >= off) ? sums[t - off] : 0;
    __syncthreads();
    sums[t] += tmp;
    __syncthreads();
  }
  int run = sums[t] - s;                             // exclusive prefix
  for (int i = beg; i < end; ++i) {
    const int c = counts[i];
    rowptr[i] = run;
    cursor[i] = run;
    run += c;
  }
  if (t == 255) rowptr[N_NODES] = run;               // == N_EDGES
}

// Scatter edges into dst-sorted arrays
__global__ __launch_bounds__(256) void scatter_kernel(const int* __restrict__ esrc,
                                                      const int* __restrict__ edst,
                                                      const float* __restrict__ ew,
                                                      int* __restrict__ cursor,
                                                      int* __restrict__ srcs_s,
                                                      float* __restrict__ ws_s) {
  const int e = blockIdx.x * 256 + threadIdx.x;
  if (e >= N_EDGES) return;
  const int d = edst[e];
  const int pos = atomicAdd(&cursor[d], 1);
  srcs_s[pos] = esrc[e];
  ws_s[pos] = ew[e];
}

// ---------------------------------------------------------------------------
// GEMM1: support1[100000,256] = x[100000,512] @ W1[512,256]   (f32)
// ---------------------------------------------------------------------------
__global__ __launch_bounds__(256) void gemm1_kernel(const float* __restrict__ x,
                                                    const float* __restrict__ W1,
                                                    float* __restrict__ out) {
  __shared__ float As[64][33];
  __shared__ float Bs[32][64];

  const int tid = threadIdx.x;
  const int tx = tid % 16;
  const int ty = tid / 16;
  const int row0 = blockIdx.x * 64;
  const int col0 = blockIdx.y * 64;

  float acc[4][4] = {};

  for (int kt = 0; kt < D_IN; kt += 32) {
    {
      const int r  = tid / 4;
      const int kk = (tid % 4) * 8;
      const int grow = row0 + r;
      if (grow < N_NODES) {
        const float* src = x + (size_t)grow * D_IN + kt + kk;
        float4 v0 = *(const float4*)(src);
        float4 v1 = *(const float4*)(src + 4);
        As[r][kk + 0] = v0.x; As[r][kk + 1] = v0.y;
        As[r][kk + 2] = v0.z; As[r][kk + 3] = v0.w;
        As[r][kk + 4] = v1.x; As[r][kk + 5] = v1.y;
        As[r][kk + 6] = v1.z; As[r][kk + 7] = v1.w;
      } else {
        for (int q = 0; q < 8; ++q) As[r][kk + q] = 0.0f;
      }
    }
    {
      const int k = tid / 8;
      const int c = (tid % 8) * 8;
      const float* src = W1 + (size_t)(kt + k) * D_HID + col0 + c;
      float4 v0 = *(const float4*)(src);
      float4 v1 = *(const float4*)(src + 4);
      *(float4*)&Bs[k][c] = v0;
      *(float4*)&Bs[k][c + 4] = v1;
    }
    __syncthreads();

#pragma unroll
    for (int k = 0; k < 32; ++k) {
      const float a0 = As[ty * 4 + 0][k];
      const float a1 = As[ty * 4 + 1][k];
      const float a2 = As[ty * 4 + 2][k];
      const float a3 = As[ty * 4 + 3][k];
      const float4 b = *(const float4*)&Bs[k][tx * 4];
      acc[0][0] += a0 * b.x; acc[0][1] += a0 * b.y; acc[0][2] += a0 * b.z; acc[0][3] += a0 * b.w;
      acc[1][0] += a1 * b.x; acc[1][1] += a1 * b.y; acc[1][2] += a1 * b.z; acc[1][3] += a1 * b.w;
      acc[2][0] += a2 * b.x; acc[2][1] += a2 * b.y; acc[2][2] += a2 * b.z; acc[2][3] += a2 * b.w;
      acc[3][0] += a3 * b.x; acc[3][1] += a3 * b.y; acc[3][2] += a3 * b.z; acc[3][3] += a3 * b.w;
    }
    __syncthreads();
  }

#pragma unroll
  for (int i = 0; i < 4; ++i) {
    const int r = row0 + ty * 4 + i;
    if (r < N_NODES) {
      float4 v = make_float4(acc[i][0], acc[i][1], acc[i][2], acc[i][3]);
      *(float4*)&out[(size_t)r * D_HID + col0 + tx * 4] = v;
    }
  }
}

// ---------------------------------------------------------------------------
// SpMM1 (CSR, no atomics) + fused bias + ReLU + dropout
// One wave per dst node; lane holds 4 consecutive feats (float4).
// ---------------------------------------------------------------------------
__global__ __launch_bounds__(256) void spmm1_csr_kernel(const float* __restrict__ sup,
                                                        const int* __restrict__ rowptr,
                                                        const int* __restrict__ srcs,
                                                        const float* __restrict__ wts,
                                                        const float* __restrict__ b1,
                                                        float* __restrict__ h) {
  const int node = blockIdx.x * 4 + (threadIdx.x >> 6);
  const int lane = threadIdx.x & 63;
  if (node >= N_NODES) return;
  const int beg = rowptr[node];
  const int end = rowptr[node + 1];

  float4 acc = make_float4(0.f, 0.f, 0.f, 0.f);
  for (int e = beg; e < end; ++e) {
    const int s = srcs[e];          // wave-uniform
    const float w = wts[e];
    const float4 v = *(const float4*)(sup + (size_t)s * D_HID + lane * 4);
    acc.x += w * v.x; acc.y += w * v.y; acc.z += w * v.z; acc.w += w * v.w;
  }

  const int col = lane * 4;
  float vals[4] = {acc.x, acc.y, acc.z, acc.w};
  float4 r;
  float* rp = (float*)&r;
#pragma unroll
  for (int j = 0; j < 4; ++j) {
    float v = vals[j] + b1[col + j];
    v = v > 0.0f ? v : 0.0f;
    unsigned o0, o1;
    threefry_0_42(0u, (unsigned)node * D_HID + col + j, o0, o1);
    const unsigned word = o0 ^ o1;
    rp[j] = (word >> 31) ? 0.0f : v * 2.0f;
  }
  *(float4*)(h + (size_t)node * D_HID + col) = r;
}

// ---------------------------------------------------------------------------
// GEMM2: support2[100000,40] = h[100000,256] @ W2[256,40]
// ---------------------------------------------------------------------------
__global__ __launch_bounds__(256) void gemm2_kernel(const float* __restrict__ h,
                                                    const float* __restrict__ W2,
                                                    float* __restrict__ out) {
  __shared__ float As[32][65];
  __shared__ float Ws[64][40];

  const int tid = threadIdx.x;
  const int row = tid / 8;
  const int cg  = tid % 8;
  const int row0 = blockIdx.x * 32;

  float acc[5] = {};

  for (int kt = 0; kt < D_HID; kt += 64) {
    {
      const int r = tid / 8;
      const int c = (tid % 8) * 8;
      const int grow = row0 + r;
      if (grow < N_NODES) {
        const float* src = h + (size_t)grow * D_HID + kt + c;
        float4 v0 = *(const float4*)(src);
        float4 v1 = *(const float4*)(src + 4);
        As[r][c + 0] = v0.x; As[r][c + 1] = v0.y; As[r][c + 2] = v0.z; As[r][c + 3] = v0.w;
        As[r][c + 4] = v1.x; As[r][c + 5] = v1.y; As[r][c + 6] = v1.z; As[r][c + 7] = v1.w;
      } else {
        for (int q = 0; q < 8; ++q) As[r][c + q] = 0.0f;
      }
    }
    {
      const int k = tid / 4;
      const int c = (tid % 4) * 10;
      const float* src = W2 + (size_t)(kt + k) * D_OUT + c;
      for (int q = 0; q < 10; ++q) Ws[k][c + q] = src[q];
    }
    __syncthreads();

#pragma unroll 8
    for (int k = 0; k < 64; ++k) {
      const float a = As[row][k];
#pragma unroll
      for (int j = 0; j < 5; ++j) acc[j] += a * Ws[k][cg * 5 + j];
    }
    __syncthreads();
  }

  const int grow = row0 + row;
  if (grow < N_NODES) {
#pragma unroll
    for (int j = 0; j < 5; ++j) out[(size_t)grow * D_OUT + cg * 5 + j] = acc[j];
  }
}

// ---------------------------------------------------------------------------
// SpMM2 (CSR, no atomics) + fused bias + log_softmax -> writes d_out directly
// One wave per dst node; lanes 0..39 hold one class each.
// ---------------------------------------------------------------------------
__global__ __launch_bounds__(256) void spmm2_csr_kernel(const float* __restrict__ sup2,
                                                        const int* __restrict__ rowptr,
                                                        const int* __restrict__ srcs,
                                                        const float* __restrict__ wts,
                                                        const float* __restrict__ b2,
                                                        float* __restrict__ out) {
  const int node = blockIdx.x * 4 + (threadIdx.x >> 6);
  const int lane = threadIdx.x & 63;
  if (node >= N_NODES) return;
  const int beg = rowptr[node];
  const int end = rowptr[node + 1];

  float acc = 0.0f;
  for (int e = beg; e < end; ++e) {
    const int s = srcs[e];
    const float w = wts[e];
    if (lane < D_OUT) acc += w * sup2[(size_t)s * D_OUT + lane];
  }

  float v = (lane < D_OUT) ? acc + b2[lane] : -INFINITY;
  float m = v;
#pragma unroll
  for (int off = 32; off > 0; off >>= 1) m = fmaxf(m, __shfl_xor(m, off, 64));
  float e = (lane < D_OUT) ? expf(v - m) : 0.0f;
  float s = e;
#pragma unroll
  for (int off = 32; off > 0; off >>= 1) s += __shfl_xor(s, off, 64);
  if (lane < D_OUT) out[(size_t)node * D_OUT + lane] = v - m - logf(s);
}

// ---------------------------------------------------------------------------
extern "C" void kernel_launch(void* const* d_in, const int* in_sizes, int n_in,
                              void* d_out, int out_size, void* d_ws, size_t ws_size,
                              hipStream_t stream) {
  const float* x    = (const float*)d_in[0];
  const int*   esrc = (const int*)d_in[1];
  const int*   edst = (const int*)d_in[2];
  const float* ew   = (const float*)d_in[3];
  const float* W1   = (const float*)d_in[4];
  const float* b1   = (const float*)d_in[5];
  const float* W2   = (const float*)d_in[6];
  const float* b2   = (const float*)d_in[7];
  float* out = (float*)d_out;

  float* ws = (float*)d_ws;
  float* support1 = ws;                          // 25,600,000 f  (102.4 MB)
  float* hbuf     = ws + 25600000;               // 25,600,000 f  (102.4 MB)
  float* support2 = ws + 51200000;               //  4,000,000 f  (16 MB)
  int*   srcs_s   = (int*)(ws + 55200000);       //  1,600,000 i
  float* ws_s     = ws + 56800000;               //  1,600,000 f
  int*   rowptr   = (int*)(ws + 58400000);       //    100,001 i
  int*   counts   = (int*)(ws + 58500008);       //    100,000 i  (doubles as cursor)
  int*   cursor   = (int*)(ws + 58600008);       //    100,000 i

  hipMemsetAsync(counts, 0, N_NODES * sizeof(int), stream);

  // CSR build
  hist_kernel<<<(N_EDGES + 255) / 256, 256, 0, stream>>>(edst, counts);
  scan_kernel<<<1, 256, 0, stream>>>(counts, rowptr, cursor);
  scatter_kernel<<<(N_EDGES + 255) / 256, 256, 0, stream>>>(esrc, edst, ew, cursor, srcs_s, ws_s);

  // layer 1
  gemm1_kernel<<<dim3(1563, 4), 256, 0, stream>>>(x, W1, support1);
  spmm1_csr_kernel<<<(N_NODES + 3) / 4, 256, 0, stream>>>(support1, rowptr, srcs_s, ws_s, b1, hbuf);

  // layer 2
  gemm2_kernel<<<(N_NODES + 31) / 32, 256, 0, stream>>>(hbuf, W2, support2);
  spmm2_csr_kernel<<<(N_NODES + 3) / 4, 256, 0, stream>>>(support2, rowptr, srcs_s, ws_s, b2, out);
}

// Round 5
// 960.164 us; speedup vs baseline: 6.3694x; 1.2883x over previous
//
#include <hip/hip_runtime.h>
#include <math.h>

#define N_NODES 100000
#define N_EDGES 1600000
#define D_IN 512
#define D_HID 256
#define D_OUT 40

typedef short short8 __attribute__((ext_vector_type(8)));
typedef float f32x4 __attribute__((ext_vector_type(4)));

// f32 -> bf16, round-to-nearest-even
static __device__ __forceinline__ short f2bf(float f) {
  unsigned u = __float_as_uint(f);
  u = (u + 0x7fffu + ((u >> 16) & 1u)) >> 16;
  return (short)u;
}

// ---------------------------------------------------------------------------
// Threefry-2x32, 20 rounds, key = (0, 42)
// ---------------------------------------------------------------------------
static __device__ __forceinline__ void threefry_0_42(unsigned x0, unsigned x1,
                                                     unsigned& o0, unsigned& o1) {
  const unsigned ks0 = 0u;
  const unsigned ks1 = 42u;
  const unsigned ks2 = 0u ^ 42u ^ 0x1BD11BDAu;
  x0 += ks0; x1 += ks1;
#define TF_R(r) { x0 += x1; x1 = (x1 << (r)) | (x1 >> (32 - (r))); x1 ^= x0; }
  TF_R(13) TF_R(15) TF_R(26) TF_R(6)
  x0 += ks1; x1 += ks2 + 1u;
  TF_R(17) TF_R(29) TF_R(16) TF_R(24)
  x0 += ks2; x1 += ks0 + 2u;
  TF_R(13) TF_R(15) TF_R(26) TF_R(6)
  x0 += ks0; x1 += ks1 + 3u;
  TF_R(17) TF_R(29) TF_R(16) TF_R(24)
  x0 += ks1; x1 += ks2 + 4u;
  TF_R(13) TF_R(15) TF_R(26) TF_R(6)
  x0 += ks2; x1 += ks0 + 5u;
#undef TF_R
  o0 = x0; o1 = x1;
}

// ---------------------------------------------------------------------------
// CSR build
// ---------------------------------------------------------------------------
__global__ __launch_bounds__(256) void hist_kernel(const int* __restrict__ edst,
                                                   int* __restrict__ counts) {
  const int e = blockIdx.x * 256 + threadIdx.x;
  if (e < N_EDGES) atomicAdd(&counts[edst[e]], 1);
}

__global__ __launch_bounds__(256) void scan_kernel(const int* __restrict__ counts,
                                                   int* __restrict__ rowptr,
                                                   int* __restrict__ cursor) {
  __shared__ int sums[256];
  const int t = threadIdx.x;
  const int chunk = (N_NODES + 255) / 256;
  const int beg = t * chunk;
  const int end = (beg + chunk < N_NODES) ? beg + chunk : N_NODES;
  int s = 0;
  for (int i = beg; i < end; ++i) s += counts[i];
  sums[t] = s;
  __syncthreads();
  for (int off = 1; off < 256; off <<= 1) {
    int tmp = (t >= off) ? sums[t - off] : 0;
    __syncthreads();
    sums[t] += tmp;
    __syncthreads();
  }
  int run = sums[t] - s;
  for (int i = beg; i < end; ++i) {
    const int c = counts[i];
    rowptr[i] = run;
    cursor[i] = run;
    run += c;
  }
  if (t == 255) rowptr[N_NODES] = run;
}

__global__ __launch_bounds__(256) void scatter_kernel(const int* __restrict__ esrc,
                                                      const int* __restrict__ edst,
                                                      const float* __restrict__ ew,
                                                      int* __restrict__ cursor,
                                                      int* __restrict__ srcs_s,
                                                      float* __restrict__ ws_s) {
  const int e = blockIdx.x * 256 + threadIdx.x;
  if (e >= N_EDGES) return;
  const int d = edst[e];
  const int pos = atomicAdd(&cursor[d], 1);
  srcs_s[pos] = esrc[e];
  ws_s[pos] = ew[e];
}

// ---------------------------------------------------------------------------
// W1 [512][256] f32  ->  W1t [256][512] bf16   (transpose + convert, 0.5 MB)
// ---------------------------------------------------------------------------
__global__ __launch_bounds__(256) void w1t_kernel(const float* __restrict__ W1,
                                                  short* __restrict__ W1t) {
  const int i = blockIdx.x * 256 + threadIdx.x;     // over 512*256
  if (i >= D_IN * D_HID) return;
  const int n = i >> 9;          // 0..255  (i / 512)
  const int k = i & 511;         // 0..511
  W1t[i] = f2bf(W1[(size_t)k * D_HID + n]);
}

// ---------------------------------------------------------------------------
// GEMM1 (bf16 MFMA): support1[100000,256] = x[100000,512] @ W1[512,256]
// BM=128, BN=256 (full width -> x read once), BK=32, 512 threads (8 waves 2x4)
// f32->bf16 conversion fused into A staging.
// ---------------------------------------------------------------------------
__global__ __launch_bounds__(512) void gemm1_mfma_kernel(const float* __restrict__ x,
                                                         const short* __restrict__ W1t,
                                                         float* __restrict__ out) {
  __shared__ __attribute__((aligned(16))) short As[128][40];  // pad->80B rows
  __shared__ __attribute__((aligned(16))) short Bs[256][40];

  const int tid  = threadIdx.x;
  const int lane = tid & 63;
  const int wid  = tid >> 6;       // 0..7
  const int wm   = wid >> 2;       // 0..1
  const int wn   = wid & 3;        // 0..3
  const int lr   = lane & 15;      // row/col within fragment
  const int lg   = lane >> 4;      // k-chunk / acc row group
  const int row0 = blockIdx.x * 128;

  f32x4 acc[4][4] = {};

  for (int kt = 0; kt < D_IN; kt += 32) {
    // stage A: 128x32 f32 -> bf16 (512 chunks of 8, one per thread)
    {
      const int m  = tid >> 2;
      const int kc = tid & 3;
      short8 v;
      const int grow = row0 + m;
      if (grow < N_NODES) {
        const float* src = x + (size_t)grow * D_IN + kt + kc * 8;
        const float4 f0 = *(const float4*)(src);
        const float4 f1 = *(const float4*)(src + 4);
        v[0] = f2bf(f0.x); v[1] = f2bf(f0.y); v[2] = f2bf(f0.z); v[3] = f2bf(f0.w);
        v[4] = f2bf(f1.x); v[5] = f2bf(f1.y); v[6] = f2bf(f1.z); v[7] = f2bf(f1.w);
      } else {
        v = (short8)0;
      }
      *(short8*)&As[m][kc * 8] = v;
    }
    // stage B: Bs[n][k] from W1t[n][kt+k] (1024 chunks, two per thread)
    {
#pragma unroll
      for (int c = 0; c < 2; ++c) {
        const int t2 = (tid << 1) | c;
        const int n  = t2 >> 2;
        const int kc = t2 & 3;
        const short8 v = *(const short8*)(W1t + (size_t)n * D_IN + kt + kc * 8);
        *(short8*)&Bs[n][kc * 8] = v;
      }
    }
    __syncthreads();

    short8 a[4], b[4];
#pragma unroll
    for (int mi = 0; mi < 4; ++mi)
      a[mi] = *(const short8*)&As[wm * 64 + mi * 16 + lr][lg * 8];
#pragma unroll
    for (int nj = 0; nj < 4; ++nj)
      b[nj] = *(const short8*)&Bs[wn * 64 + nj * 16 + lr][lg * 8];

#pragma unroll
    for (int mi = 0; mi < 4; ++mi)
#pragma unroll
      for (int nj = 0; nj < 4; ++nj)
        acc[mi][nj] = __builtin_amdgcn_mfma_f32_16x16x32_bf16(a[mi], b[nj], acc[mi][nj], 0, 0, 0);

    __syncthreads();
  }

  // write out: C/D layout col = lane&15, row = (lane>>4)*4 + reg
#pragma unroll
  for (int mi = 0; mi < 4; ++mi) {
#pragma unroll
    for (int nj = 0; nj < 4; ++nj) {
      const int gcol = wn * 64 + nj * 16 + lr;
#pragma unroll
      for (int r = 0; r < 4; ++r) {
        const int grow = row0 + wm * 64 + mi * 16 + lg * 4 + r;
        if (grow < N_NODES) out[(size_t)grow * D_HID + gcol] = acc[mi][nj][r];
      }
    }
  }
}

// ---------------------------------------------------------------------------
// SpMM1 (CSR) + fused bias + ReLU + dropout
// ---------------------------------------------------------------------------
__global__ __launch_bounds__(256) void spmm1_csr_kernel(const float* __restrict__ sup,
                                                        const int* __restrict__ rowptr,
                                                        const int* __restrict__ srcs,
                                                        const float* __restrict__ wts,
                                                        const float* __restrict__ b1,
                                                        float* __restrict__ h) {
  const int node = blockIdx.x * 4 + (threadIdx.x >> 6);
  const int lane = threadIdx.x & 63;
  if (node >= N_NODES) return;
  const int beg = rowptr[node];
  const int end = rowptr[node + 1];

  float4 acc = make_float4(0.f, 0.f, 0.f, 0.f);
  for (int e = beg; e < end; ++e) {
    const int s = srcs[e];
    const float w = wts[e];
    const float4 v = *(const float4*)(sup + (size_t)s * D_HID + lane * 4);
    acc.x += w * v.x; acc.y += w * v.y; acc.z += w * v.z; acc.w += w * v.w;
  }

  const int col = lane * 4;
  float vals[4] = {acc.x, acc.y, acc.z, acc.w};
  float4 r;
  float* rp = (float*)&r;
#pragma unroll
  for (int j = 0; j < 4; ++j) {
    float v = vals[j] + b1[col + j];
    v = v > 0.0f ? v : 0.0f;
    unsigned o0, o1;
    threefry_0_42(0u, (unsigned)node * D_HID + col + j, o0, o1);
    const unsigned word = o0 ^ o1;
    rp[j] = (word >> 31) ? 0.0f : v * 2.0f;
  }
  *(float4*)(h + (size_t)node * D_HID + col) = r;
}

// ---------------------------------------------------------------------------
// GEMM2: support2[100000,40] = h[100000,256] @ W2[256,40]   (f32)
// ---------------------------------------------------------------------------
__global__ __launch_bounds__(256) void gemm2_kernel(const float* __restrict__ h,
                                                    const float* __restrict__ W2,
                                                    float* __restrict__ out) {
  __shared__ float As[32][65];
  __shared__ float Ws[64][40];

  const int tid = threadIdx.x;
  const int row = tid / 8;
  const int cg  = tid % 8;
  const int row0 = blockIdx.x * 32;

  float acc[5] = {};

  for (int kt = 0; kt < D_HID; kt += 64) {
    {
      const int r = tid / 8;
      const int c = (tid % 8) * 8;
      const int grow = row0 + r;
      if (grow < N_NODES) {
        const float* src = h + (size_t)grow * D_HID + kt + c;
        float4 v0 = *(const float4*)(src);
        float4 v1 = *(const float4*)(src + 4);
        As[r][c + 0] = v0.x; As[r][c + 1] = v0.y; As[r][c + 2] = v0.z; As[r][c + 3] = v0.w;
        As[r][c + 4] = v1.x; As[r][c + 5] = v1.y; As[r][c + 6] = v1.z; As[r][c + 7] = v1.w;
      } else {
        for (int q = 0; q < 8; ++q) As[r][c + q] = 0.0f;
      }
    }
    {
      const int k = tid / 4;
      const int c = (tid % 4) * 10;
      const float* src = W2 + (size_t)(kt + k) * D_OUT + c;
      for (int q = 0; q < 10; ++q) Ws[k][c + q] = src[q];
    }
    __syncthreads();

#pragma unroll 8
    for (int k = 0; k < 64; ++k) {
      const float a = As[row][k];
#pragma unroll
      for (int j = 0; j < 5; ++j) acc[j] += a * Ws[k][cg * 5 + j];
    }
    __syncthreads();
  }

  const int grow = row0 + row;
  if (grow < N_NODES) {
#pragma unroll
    for (int j = 0; j < 5; ++j) out[(size_t)grow * D_OUT + cg * 5 + j] = acc[j];
  }
}

// ---------------------------------------------------------------------------
// SpMM2 (CSR) + fused bias + log_softmax -> d_out
// ---------------------------------------------------------------------------
__global__ __launch_bounds__(256) void spmm2_csr_kernel(const float* __restrict__ sup2,
                                                        const int* __restrict__ rowptr,
                                                        const int* __restrict__ srcs,
                                                        const float* __restrict__ wts,
                                                        const float* __restrict__ b2,
                                                        float* __restrict__ out) {
  const int node = blockIdx.x * 4 + (threadIdx.x >> 6);
  const int lane = threadIdx.x & 63;
  if (node >= N_NODES) return;
  const int beg = rowptr[node];
  const int end = rowptr[node + 1];

  float acc = 0.0f;
  for (int e = beg; e < end; ++e) {
    const int s = srcs[e];
    const float w = wts[e];
    if (lane < D_OUT) acc += w * sup2[(size_t)s * D_OUT + lane];
  }

  float v = (lane < D_OUT) ? acc + b2[lane] : -INFINITY;
  float m = v;
#pragma unroll
  for (int off = 32; off > 0; off >>= 1) m = fmaxf(m, __shfl_xor(m, off, 64));
  float e = (lane < D_OUT) ? expf(v - m) : 0.0f;
  float s = e;
#pragma unroll
  for (int off = 32; off > 0; off >>= 1) s += __shfl_xor(s, off, 64);
  if (lane < D_OUT) out[(size_t)node * D_OUT + lane] = v - m - logf(s);
}

// ---------------------------------------------------------------------------
extern "C" void kernel_launch(void* const* d_in, const int* in_sizes, int n_in,
                              void* d_out, int out_size, void* d_ws, size_t ws_size,
                              hipStream_t stream) {
  const float* x    = (const float*)d_in[0];
  const int*   esrc = (const int*)d_in[1];
  const int*   edst = (const int*)d_in[2];
  const float* ew   = (const float*)d_in[3];
  const float* W1   = (const float*)d_in[4];
  const float* b1   = (const float*)d_in[5];
  const float* W2   = (const float*)d_in[6];
  const float* b2   = (const float*)d_in[7];
  float* out = (float*)d_out;

  float* ws = (float*)d_ws;
  float* support1 = ws;                          // 25,600,000 f  (102.4 MB)
  float* hbuf     = ws + 25600000;               // 25,600,000 f  (102.4 MB)
  float* support2 = ws + 51200000;               //  4,000,000 f  (16 MB)
  int*   srcs_s   = (int*)(ws + 55200000);       //  1,600,000 i
  float* ws_s     = ws + 56800000;               //  1,600,000 f
  int*   rowptr   = (int*)(ws + 58400000);       //    100,001 i
  int*   counts   = (int*)(ws + 58500008);       //    100,000 i
  int*   cursor   = (int*)(ws + 58600008);       //    100,000 i
  short* W1t      = (short*)(ws + 58700008);     //    131,072 bf16 (0.25 MB)

  hipMemsetAsync(counts, 0, N_NODES * sizeof(int), stream);

  // CSR build + weight prep
  hist_kernel<<<(N_EDGES + 255) / 256, 256, 0, stream>>>(edst, counts);
  w1t_kernel<<<(D_IN * D_HID + 255) / 256, 256, 0, stream>>>(W1, W1t);
  scan_kernel<<<1, 256, 0, stream>>>(counts, rowptr, cursor);
  scatter_kernel<<<(N_EDGES + 255) / 256, 256, 0, stream>>>(esrc, edst, ew, cursor, srcs_s, ws_s);

  // layer 1
  gemm1_mfma_kernel<<<(N_NODES + 127) / 128, 512, 0, stream>>>(x, W1t, support1);
  spmm1_csr_kernel<<<(N_NODES + 3) / 4, 256, 0, stream>>>(support1, rowptr, srcs_s, ws_s, b1, hbuf);

  // layer 2
  gemm2_kernel<<<(N_NODES + 31) / 32, 256, 0, stream>>>(hbuf, W2, support2);
  spmm2_csr_kernel<<<(N_NODES + 3) / 4, 256, 0, stream>>>(support2, rowptr, srcs_s, ws_s, b2, out);
}

// Round 6
// 864.711 us; speedup vs baseline: 7.0725x; 1.1104x over previous
//
#include <hip/hip_runtime.h>
#include <math.h>

#define N_NODES 100000
#define N_EDGES 1600000
#define D_IN 512
#define D_HID 256
#define D_OUT 40

typedef short short8 __attribute__((ext_vector_type(8)));
typedef short short4v __attribute__((ext_vector_type(4)));
typedef float f32x4 __attribute__((ext_vector_type(4)));

// f32 -> bf16, round-to-nearest-even
static __device__ __forceinline__ short f2bf(float f) {
  unsigned u = __float_as_uint(f);
  u = (u + 0x7fffu + ((u >> 16) & 1u)) >> 16;
  return (short)u;
}
static __device__ __forceinline__ float bf2f(unsigned short h) {
  return __uint_as_float(((unsigned)h) << 16);
}

// ---------------------------------------------------------------------------
// Threefry-2x32, 20 rounds, key = (0, 42)
// ---------------------------------------------------------------------------
static __device__ __forceinline__ void threefry_0_42(unsigned x0, unsigned x1,
                                                     unsigned& o0, unsigned& o1) {
  const unsigned ks0 = 0u;
  const unsigned ks1 = 42u;
  const unsigned ks2 = 0u ^ 42u ^ 0x1BD11BDAu;
  x0 += ks0; x1 += ks1;
#define TF_R(r) { x0 += x1; x1 = (x1 << (r)) | (x1 >> (32 - (r))); x1 ^= x0; }
  TF_R(13) TF_R(15) TF_R(26) TF_R(6)
  x0 += ks1; x1 += ks2 + 1u;
  TF_R(17) TF_R(29) TF_R(16) TF_R(24)
  x0 += ks2; x1 += ks0 + 2u;
  TF_R(13) TF_R(15) TF_R(26) TF_R(6)
  x0 += ks0; x1 += ks1 + 3u;
  TF_R(17) TF_R(29) TF_R(16) TF_R(24)
  x0 += ks1; x1 += ks2 + 4u;
  TF_R(13) TF_R(15) TF_R(26) TF_R(6)
  x0 += ks2; x1 += ks0 + 5u;
#undef TF_R
  o0 = x0; o1 = x1;
}

// ---------------------------------------------------------------------------
// CSR build
// ---------------------------------------------------------------------------
__global__ __launch_bounds__(256) void hist_kernel(const int* __restrict__ edst,
                                                   int* __restrict__ counts) {
  const int e = blockIdx.x * 256 + threadIdx.x;
  if (e < N_EDGES) atomicAdd(&counts[edst[e]], 1);
}

__global__ __launch_bounds__(256) void scan_kernel(const int* __restrict__ counts,
                                                   int* __restrict__ rowptr,
                                                   int* __restrict__ cursor) {
  __shared__ int sums[256];
  const int t = threadIdx.x;
  const int chunk = (N_NODES + 255) / 256;
  const int beg = t * chunk;
  const int end = (beg + chunk < N_NODES) ? beg + chunk : N_NODES;
  int s = 0;
  for (int i = beg; i < end; ++i) s += counts[i];
  sums[t] = s;
  __syncthreads();
  for (int off = 1; off < 256; off <<= 1) {
    int tmp = (t >= off) ? sums[t - off] : 0;
    __syncthreads();
    sums[t] += tmp;
    __syncthreads();
  }
  int run = sums[t] - s;
  for (int i = beg; i < end; ++i) {
    const int c = counts[i];
    rowptr[i] = run;
    cursor[i] = run;
    run += c;
  }
  if (t == 255) rowptr[N_NODES] = run;
}

__global__ __launch_bounds__(256) void scatter_kernel(const int* __restrict__ esrc,
                                                      const int* __restrict__ edst,
                                                      const float* __restrict__ ew,
                                                      int* __restrict__ cursor,
                                                      int* __restrict__ srcs_s,
                                                      float* __restrict__ ws_s) {
  const int e = blockIdx.x * 256 + threadIdx.x;
  if (e >= N_EDGES) return;
  const int d = edst[e];
  const int pos = atomicAdd(&cursor[d], 1);
  srcs_s[pos] = esrc[e];
  ws_s[pos] = ew[e];
}

// ---------------------------------------------------------------------------
// W1 [512][256] f32 -> W1t [256][512] bf16
// ---------------------------------------------------------------------------
__global__ __launch_bounds__(256) void w1t_kernel(const float* __restrict__ W1,
                                                  short* __restrict__ W1t) {
  const int i = blockIdx.x * 256 + threadIdx.x;
  if (i >= D_IN * D_HID) return;
  const int n = i >> 9;
  const int k = i & 511;
  W1t[i] = f2bf(W1[(size_t)k * D_HID + n]);
}

// W2 [256][40] f32 -> W2t [48][256] bf16 (cols 40..47 zero)
__global__ __launch_bounds__(256) void w2t_kernel(const float* __restrict__ W2,
                                                  short* __restrict__ W2t) {
  const int i = blockIdx.x * 256 + threadIdx.x;
  if (i >= 48 * D_HID) return;
  const int n = i >> 8;          // 0..47
  const int k = i & 255;         // 0..255
  W2t[i] = (n < D_OUT) ? f2bf(W2[(size_t)k * D_OUT + n]) : (short)0;
}

// ---------------------------------------------------------------------------
// GEMM1 (bf16 MFMA): support1(bf16)[100000,256] = x @ W1
// BM=128, BN=256, BK=32, 512 threads (8 waves 2x4)
// ---------------------------------------------------------------------------
__global__ __launch_bounds__(512) void gemm1_mfma_kernel(const float* __restrict__ x,
                                                         const short* __restrict__ W1t,
                                                         short* __restrict__ out) {
  __shared__ __attribute__((aligned(16))) short As[128][40];
  __shared__ __attribute__((aligned(16))) short Bs[256][40];

  const int tid  = threadIdx.x;
  const int lane = tid & 63;
  const int wid  = tid >> 6;
  const int wm   = wid >> 2;
  const int wn   = wid & 3;
  const int lr   = lane & 15;
  const int lg   = lane >> 4;
  const int row0 = blockIdx.x * 128;

  f32x4 acc[4][4] = {};

  for (int kt = 0; kt < D_IN; kt += 32) {
    {
      const int m  = tid >> 2;
      const int kc = tid & 3;
      short8 v;
      const int grow = row0 + m;
      if (grow < N_NODES) {
        const float* src = x + (size_t)grow * D_IN + kt + kc * 8;
        const float4 f0 = *(const float4*)(src);
        const float4 f1 = *(const float4*)(src + 4);
        v[0] = f2bf(f0.x); v[1] = f2bf(f0.y); v[2] = f2bf(f0.z); v[3] = f2bf(f0.w);
        v[4] = f2bf(f1.x); v[5] = f2bf(f1.y); v[6] = f2bf(f1.z); v[7] = f2bf(f1.w);
      } else {
        v = (short8)0;
      }
      *(short8*)&As[m][kc * 8] = v;
    }
    {
#pragma unroll
      for (int c = 0; c < 2; ++c) {
        const int t2 = (tid << 1) | c;
        const int n  = t2 >> 2;
        const int kc = t2 & 3;
        const short8 v = *(const short8*)(W1t + (size_t)n * D_IN + kt + kc * 8);
        *(short8*)&Bs[n][kc * 8] = v;
      }
    }
    __syncthreads();

    short8 a[4], b[4];
#pragma unroll
    for (int mi = 0; mi < 4; ++mi)
      a[mi] = *(const short8*)&As[wm * 64 + mi * 16 + lr][lg * 8];
#pragma unroll
    for (int nj = 0; nj < 4; ++nj)
      b[nj] = *(const short8*)&Bs[wn * 64 + nj * 16 + lr][lg * 8];

#pragma unroll
    for (int mi = 0; mi < 4; ++mi)
#pragma unroll
      for (int nj = 0; nj < 4; ++nj)
        acc[mi][nj] = __builtin_amdgcn_mfma_f32_16x16x32_bf16(a[mi], b[nj], acc[mi][nj], 0, 0, 0);

    __syncthreads();
  }

#pragma unroll
  for (int mi = 0; mi < 4; ++mi) {
#pragma unroll
    for (int nj = 0; nj < 4; ++nj) {
      const int gcol = wn * 64 + nj * 16 + lr;
#pragma unroll
      for (int r = 0; r < 4; ++r) {
        const int grow = row0 + wm * 64 + mi * 16 + lg * 4 + r;
        if (grow < N_NODES) out[(size_t)grow * D_HID + gcol] = f2bf(acc[mi][nj][r]);
      }
    }
  }
}

// ---------------------------------------------------------------------------
// SpMM1 (CSR) + fused bias + ReLU + dropout; bf16 in, bf16 out, f32 accum
// One wave per dst node; lane holds 4 consecutive feats.
// ---------------------------------------------------------------------------
__global__ __launch_bounds__(256) void spmm1_csr_kernel(const short* __restrict__ sup,
                                                        const int* __restrict__ rowptr,
                                                        const int* __restrict__ srcs,
                                                        const float* __restrict__ wts,
                                                        const float* __restrict__ b1,
                                                        short* __restrict__ h) {
  const int node = blockIdx.x * 4 + (threadIdx.x >> 6);
  const int lane = threadIdx.x & 63;
  if (node >= N_NODES) return;
  const int beg = rowptr[node];
  const int end = rowptr[node + 1];

  float acc[4] = {0.f, 0.f, 0.f, 0.f};
  for (int e = beg; e < end; ++e) {
    const int s = srcs[e];          // wave-uniform
    const float w = wts[e];
    const short4v v = *(const short4v*)(sup + (size_t)s * D_HID + lane * 4);
    acc[0] += w * bf2f((unsigned short)v[0]);
    acc[1] += w * bf2f((unsigned short)v[1]);
    acc[2] += w * bf2f((unsigned short)v[2]);
    acc[3] += w * bf2f((unsigned short)v[3]);
  }

  const int col = lane * 4;
  short4v r;
#pragma unroll
  for (int j = 0; j < 4; ++j) {
    float v = acc[j] + b1[col + j];
    v = v > 0.0f ? v : 0.0f;
    unsigned o0, o1;
    threefry_0_42(0u, (unsigned)node * D_HID + col + j, o0, o1);
    const unsigned word = o0 ^ o1;
    r[j] = (word >> 31) ? (short)0 : f2bf(v * 2.0f);
  }
  *(short4v*)(h + (size_t)node * D_HID + col) = r;
}

// ---------------------------------------------------------------------------
// GEMM2 (bf16 MFMA): support2(f32)[100000,40] = h(bf16) @ W2
// BM=128, BN=48 (pad), BK=32, 256 threads (4 waves, each M=32 x N=48)
// ---------------------------------------------------------------------------
__global__ __launch_bounds__(256) void gemm2_mfma_kernel(const short* __restrict__ h,
                                                         const short* __restrict__ W2t,
                                                         float* __restrict__ out) {
  __shared__ __attribute__((aligned(16))) short As[128][40];
  __shared__ __attribute__((aligned(16))) short Bs[48][40];

  const int tid  = threadIdx.x;
  const int lane = tid & 63;
  const int wm   = tid >> 6;       // 0..3 (M group of 32)
  const int lr   = lane & 15;
  const int lg   = lane >> 4;
  const int row0 = blockIdx.x * 128;

  f32x4 acc[2][3] = {};

  for (int kt = 0; kt < D_HID; kt += 32) {
    // stage A: 128 rows x 32 k bf16 (512 chunks of short8, 2 per thread)
    {
#pragma unroll
      for (int c = 0; c < 2; ++c) {
        const int t2 = (tid << 1) | c;
        const int m  = t2 >> 2;
        const int kc = t2 & 3;
        const int grow = row0 + m;
        short8 v = (short8)0;
        if (grow < N_NODES)
          v = *(const short8*)(h + (size_t)grow * D_HID + kt + kc * 8);
        *(short8*)&As[m][kc * 8] = v;
      }
    }
    // stage B: 48 x 32 (192 chunks)
    if (tid < 192) {
      const int n  = tid >> 2;
      const int kc = tid & 3;
      const short8 v = *(const short8*)(W2t + (size_t)n * D_HID + kt + kc * 8);
      *(short8*)&Bs[n][kc * 8] = v;
    }
    __syncthreads();

    short8 a[2], b[3];
#pragma unroll
    for (int mi = 0; mi < 2; ++mi)
      a[mi] = *(const short8*)&As[wm * 32 + mi * 16 + lr][lg * 8];
#pragma unroll
    for (int nj = 0; nj < 3; ++nj)
      b[nj] = *(const short8*)&Bs[nj * 16 + lr][lg * 8];

#pragma unroll
    for (int mi = 0; mi < 2; ++mi)
#pragma unroll
      for (int nj = 0; nj < 3; ++nj)
        acc[mi][nj] = __builtin_amdgcn_mfma_f32_16x16x32_bf16(a[mi], b[nj], acc[mi][nj], 0, 0, 0);

    __syncthreads();
  }

#pragma unroll
  for (int mi = 0; mi < 2; ++mi) {
#pragma unroll
    for (int nj = 0; nj < 3; ++nj) {
      const int gcol = nj * 16 + lr;
      if (gcol < D_OUT) {
#pragma unroll
        for (int r = 0; r < 4; ++r) {
          const int grow = row0 + wm * 32 + mi * 16 + lg * 4 + r;
          if (grow < N_NODES) out[(size_t)grow * D_OUT + gcol] = acc[mi][nj][r];
        }
      }
    }
  }
}

// ---------------------------------------------------------------------------
// SpMM2 (CSR) + fused bias + log_softmax -> d_out
// ---------------------------------------------------------------------------
__global__ __launch_bounds__(256) void spmm2_csr_kernel(const float* __restrict__ sup2,
                                                        const int* __restrict__ rowptr,
                                                        const int* __restrict__ srcs,
                                                        const float* __restrict__ wts,
                                                        const float* __restrict__ b2,
                                                        float* __restrict__ out) {
  const int node = blockIdx.x * 4 + (threadIdx.x >> 6);
  const int lane = threadIdx.x & 63;
  if (node >= N_NODES) return;
  const int beg = rowptr[node];
  const int end = rowptr[node + 1];

  float acc = 0.0f;
  for (int e = beg; e < end; ++e) {
    const int s = srcs[e];
    const float w = wts[e];
    if (lane < D_OUT) acc += w * sup2[(size_t)s * D_OUT + lane];
  }

  float v = (lane < D_OUT) ? acc + b2[lane] : -INFINITY;
  float m = v;
#pragma unroll
  for (int off = 32; off > 0; off >>= 1) m = fmaxf(m, __shfl_xor(m, off, 64));
  float e = (lane < D_OUT) ? expf(v - m) : 0.0f;
  float s = e;
#pragma unroll
  for (int off = 32; off > 0; off >>= 1) s += __shfl_xor(s, off, 64);
  if (lane < D_OUT) out[(size_t)node * D_OUT + lane] = v - m - logf(s);
}

// ---------------------------------------------------------------------------
extern "C" void kernel_launch(void* const* d_in, const int* in_sizes, int n_in,
                              void* d_out, int out_size, void* d_ws, size_t ws_size,
                              hipStream_t stream) {
  const float* x    = (const float*)d_in[0];
  const int*   esrc = (const int*)d_in[1];
  const int*   edst = (const int*)d_in[2];
  const float* ew   = (const float*)d_in[3];
  const float* W1   = (const float*)d_in[4];
  const float* b1   = (const float*)d_in[5];
  const float* W2   = (const float*)d_in[6];
  const float* b2   = (const float*)d_in[7];
  float* out = (float*)d_out;

  float* ws = (float*)d_ws;
  short* support1 = (short*)ws;                  // 25,600,000 bf16 (51.2 MB)
  short* hbuf     = (short*)(ws + 12800000);     // 25,600,000 bf16 (51.2 MB)
  float* support2 = ws + 25600000;               //  4,000,000 f32  (16 MB)
  int*   srcs_s   = (int*)(ws + 29600000);       //  1,600,000 i
  float* ws_s     = ws + 31200000;               //  1,600,000 f
  int*   rowptr   = (int*)(ws + 32800000);       //    100,001 i
  int*   counts   = (int*)(ws + 32900008);       //    100,000 i
  int*   cursor   = (int*)(ws + 33000008);       //    100,000 i
  short* W1t      = (short*)(ws + 33100008);     //    131,072 bf16
  short* W2t      = (short*)(ws + 33165544);     //     12,288 bf16

  hipMemsetAsync(counts, 0, N_NODES * sizeof(int), stream);

  // CSR build + weight prep
  hist_kernel<<<(N_EDGES + 255) / 256, 256, 0, stream>>>(edst, counts);
  w1t_kernel<<<(D_IN * D_HID + 255) / 256, 256, 0, stream>>>(W1, W1t);
  w2t_kernel<<<(48 * D_HID + 255) / 256, 256, 0, stream>>>(W2, W2t);
  scan_kernel<<<1, 256, 0, stream>>>(counts, rowptr, cursor);
  scatter_kernel<<<(N_EDGES + 255) / 256, 256, 0, stream>>>(esrc, edst, ew, cursor, srcs_s, ws_s);

  // layer 1
  gemm1_mfma_kernel<<<(N_NODES + 127) / 128, 512, 0, stream>>>(x, W1t, support1);
  spmm1_csr_kernel<<<(N_NODES + 3) / 4, 256, 0, stream>>>(support1, rowptr, srcs_s, ws_s, b1, hbuf);

  // layer 2
  gemm2_mfma_kernel<<<(N_NODES + 127) / 128, 256, 0, stream>>>(hbuf, W2t, support2);
  spmm2_csr_kernel<<<(N_NODES + 3) / 4, 256, 0, stream>>>(support2, rowptr, srcs_s, ws_s, b2, out);
}

// Round 7
// 646.451 us; speedup vs baseline: 9.4604x; 1.3376x over previous
//
#include <hip/hip_runtime.h>
#include <math.h>

#define N_NODES 100000
#define N_EDGES 1600000
#define D_IN 512
#define D_HID 256
#define D_OUT 40
#define SCAN_BLOCKS ((N_NODES + 255) / 256)   // 391

typedef short short8 __attribute__((ext_vector_type(8)));
typedef short short4v __attribute__((ext_vector_type(4)));
typedef float f32x4 __attribute__((ext_vector_type(4)));

// f32 -> bf16, round-to-nearest-even
static __device__ __forceinline__ short f2bf(float f) {
  unsigned u = __float_as_uint(f);
  u = (u + 0x7fffu + ((u >> 16) & 1u)) >> 16;
  return (short)u;
}
static __device__ __forceinline__ float bf2f(unsigned short h) {
  return __uint_as_float(((unsigned)h) << 16);
}

// ---------------------------------------------------------------------------
// Threefry-2x32, 20 rounds, key = (0, 42)
// ---------------------------------------------------------------------------
static __device__ __forceinline__ void threefry_0_42(unsigned x0, unsigned x1,
                                                     unsigned& o0, unsigned& o1) {
  const unsigned ks0 = 0u;
  const unsigned ks1 = 42u;
  const unsigned ks2 = 0u ^ 42u ^ 0x1BD11BDAu;
  x0 += ks0; x1 += ks1;
#define TF_R(r) { x0 += x1; x1 = (x1 << (r)) | (x1 >> (32 - (r))); x1 ^= x0; }
  TF_R(13) TF_R(15) TF_R(26) TF_R(6)
  x0 += ks1; x1 += ks2 + 1u;
  TF_R(17) TF_R(29) TF_R(16) TF_R(24)
  x0 += ks2; x1 += ks0 + 2u;
  TF_R(13) TF_R(15) TF_R(26) TF_R(6)
  x0 += ks0; x1 += ks1 + 3u;
  TF_R(17) TF_R(29) TF_R(16) TF_R(24)
  x0 += ks1; x1 += ks2 + 4u;
  TF_R(13) TF_R(15) TF_R(26) TF_R(6)
  x0 += ks2; x1 += ks0 + 5u;
#undef TF_R
  o0 = x0; o1 = x1;
}

// ---------------------------------------------------------------------------
// CSR build
// ---------------------------------------------------------------------------
__global__ __launch_bounds__(256) void hist_kernel(const int* __restrict__ edst,
                                                   int* __restrict__ counts) {
  const int e = blockIdx.x * 256 + threadIdx.x;
  if (e < N_EDGES) atomicAdd(&counts[edst[e]], 1);
}

// stage 1: per-block sums of counts
__global__ __launch_bounds__(256) void block_sum_kernel(const int* __restrict__ counts,
                                                        int* __restrict__ bsums) {
  __shared__ int red[256];
  const int t = threadIdx.x;
  const int i = blockIdx.x * 256 + t;
  red[t] = (i < N_NODES) ? counts[i] : 0;
  __syncthreads();
#pragma unroll
  for (int off = 128; off > 0; off >>= 1) {
    if (t < off) red[t] += red[t + off];
    __syncthreads();
  }
  if (t == 0) bsums[blockIdx.x] = red[0];
}

// stage 2: one block scans the 391 block sums (exclusive)
__global__ __launch_bounds__(512) void bsum_scan_kernel(const int* __restrict__ bsums,
                                                        int* __restrict__ boffs) {
  __shared__ int tmp[512];
  const int t = threadIdx.x;
  const int v = (t < SCAN_BLOCKS) ? bsums[t] : 0;
  tmp[t] = v;
  __syncthreads();
  for (int off = 1; off < 512; off <<= 1) {
    const int add = (t >= off) ? tmp[t - off] : 0;
    __syncthreads();
    tmp[t] += add;
    __syncthreads();
  }
  if (t < SCAN_BLOCKS) boffs[t] = tmp[t] - v;   // exclusive prefix
}

// stage 3: per-block scan + offset -> rowptr, cursor
__global__ __launch_bounds__(256) void scan_apply_kernel(const int* __restrict__ counts,
                                                         const int* __restrict__ boffs,
                                                         int* __restrict__ rowptr,
                                                         int* __restrict__ cursor) {
  __shared__ int tmp[256];
  const int t = threadIdx.x;
  const int i = blockIdx.x * 256 + t;
  const int v = (i < N_NODES) ? counts[i] : 0;
  tmp[t] = v;
  __syncthreads();
  for (int off = 1; off < 256; off <<= 1) {
    const int add = (t >= off) ? tmp[t - off] : 0;
    __syncthreads();
    tmp[t] += add;
    __syncthreads();
  }
  const int excl = boffs[blockIdx.x] + tmp[t] - v;
  if (i < N_NODES) {
    rowptr[i] = excl;
    cursor[i] = excl;
    if (i == N_NODES - 1) rowptr[N_NODES] = excl + v;
  }
}

__global__ __launch_bounds__(256) void scatter_kernel(const int* __restrict__ esrc,
                                                      const int* __restrict__ edst,
                                                      const float* __restrict__ ew,
                                                      int* __restrict__ cursor,
                                                      int* __restrict__ srcs_s,
                                                      float* __restrict__ ws_s) {
  const int e = blockIdx.x * 256 + threadIdx.x;
  if (e >= N_EDGES) return;
  const int d = edst[e];
  const int pos = atomicAdd(&cursor[d], 1);
  srcs_s[pos] = esrc[e];
  ws_s[pos] = ew[e];
}

// ---------------------------------------------------------------------------
// W1 [512][256] f32 -> W1t [256][512] bf16
// ---------------------------------------------------------------------------
__global__ __launch_bounds__(256) void w1t_kernel(const float* __restrict__ W1,
                                                  short* __restrict__ W1t) {
  const int i = blockIdx.x * 256 + threadIdx.x;
  if (i >= D_IN * D_HID) return;
  const int n = i >> 9;
  const int k = i & 511;
  W1t[i] = f2bf(W1[(size_t)k * D_HID + n]);
}

// W2 [256][40] f32 -> W2t [48][256] bf16 (cols 40..47 zero)
__global__ __launch_bounds__(256) void w2t_kernel(const float* __restrict__ W2,
                                                  short* __restrict__ W2t) {
  const int i = blockIdx.x * 256 + threadIdx.x;
  if (i >= 48 * D_HID) return;
  const int n = i >> 8;
  const int k = i & 255;
  W2t[i] = (n < D_OUT) ? f2bf(W2[(size_t)k * D_OUT + n]) : (short)0;
}

// ---------------------------------------------------------------------------
// GEMM1 (bf16 MFMA): support1(bf16)[100000,256] = x @ W1
// BM=128, BN=256, BK=32, 512 threads (8 waves 2x4)
// ---------------------------------------------------------------------------
__global__ __launch_bounds__(512) void gemm1_mfma_kernel(const float* __restrict__ x,
                                                         const short* __restrict__ W1t,
                                                         short* __restrict__ out) {
  __shared__ __attribute__((aligned(16))) short As[128][40];
  __shared__ __attribute__((aligned(16))) short Bs[256][40];

  const int tid  = threadIdx.x;
  const int lane = tid & 63;
  const int wid  = tid >> 6;
  const int wm   = wid >> 2;
  const int wn   = wid & 3;
  const int lr   = lane & 15;
  const int lg   = lane >> 4;
  const int row0 = blockIdx.x * 128;

  f32x4 acc[4][4] = {};

  for (int kt = 0; kt < D_IN; kt += 32) {
    {
      const int m  = tid >> 2;
      const int kc = tid & 3;
      short8 v;
      const int grow = row0 + m;
      if (grow < N_NODES) {
        const float* src = x + (size_t)grow * D_IN + kt + kc * 8;
        const float4 f0 = *(const float4*)(src);
        const float4 f1 = *(const float4*)(src + 4);
        v[0] = f2bf(f0.x); v[1] = f2bf(f0.y); v[2] = f2bf(f0.z); v[3] = f2bf(f0.w);
        v[4] = f2bf(f1.x); v[5] = f2bf(f1.y); v[6] = f2bf(f1.z); v[7] = f2bf(f1.w);
      } else {
        v = (short8)0;
      }
      *(short8*)&As[m][kc * 8] = v;
    }
    {
#pragma unroll
      for (int c = 0; c < 2; ++c) {
        const int t2 = (tid << 1) | c;
        const int n  = t2 >> 2;
        const int kc = t2 & 3;
        const short8 v = *(const short8*)(W1t + (size_t)n * D_IN + kt + kc * 8);
        *(short8*)&Bs[n][kc * 8] = v;
      }
    }
    __syncthreads();

    short8 a[4], b[4];
#pragma unroll
    for (int mi = 0; mi < 4; ++mi)
      a[mi] = *(const short8*)&As[wm * 64 + mi * 16 + lr][lg * 8];
#pragma unroll
    for (int nj = 0; nj < 4; ++nj)
      b[nj] = *(const short8*)&Bs[wn * 64 + nj * 16 + lr][lg * 8];

#pragma unroll
    for (int mi = 0; mi < 4; ++mi)
#pragma unroll
      for (int nj = 0; nj < 4; ++nj)
        acc[mi][nj] = __builtin_amdgcn_mfma_f32_16x16x32_bf16(a[mi], b[nj], acc[mi][nj], 0, 0, 0);

    __syncthreads();
  }

#pragma unroll
  for (int mi = 0; mi < 4; ++mi) {
#pragma unroll
    for (int nj = 0; nj < 4; ++nj) {
      const int gcol = wn * 64 + nj * 16 + lr;
#pragma unroll
      for (int r = 0; r < 4; ++r) {
        const int grow = row0 + wm * 64 + mi * 16 + lg * 4 + r;
        if (grow < N_NODES) out[(size_t)grow * D_HID + gcol] = f2bf(acc[mi][nj][r]);
      }
    }
  }
}

// ---------------------------------------------------------------------------
// SpMM1 (CSR) + fused bias + ReLU + dropout; bf16 in, bf16 out, f32 accum
// ---------------------------------------------------------------------------
__global__ __launch_bounds__(256) void spmm1_csr_kernel(const short* __restrict__ sup,
                                                        const int* __restrict__ rowptr,
                                                        const int* __restrict__ srcs,
                                                        const float* __restrict__ wts,
                                                        const float* __restrict__ b1,
                                                        short* __restrict__ h) {
  const int node = blockIdx.x * 4 + (threadIdx.x >> 6);
  const int lane = threadIdx.x & 63;
  if (node >= N_NODES) return;
  const int beg = rowptr[node];
  const int end = rowptr[node + 1];

  float acc[4] = {0.f, 0.f, 0.f, 0.f};
  for (int e = beg; e < end; ++e) {
    const int s = srcs[e];
    const float w = wts[e];
    const short4v v = *(const short4v*)(sup + (size_t)s * D_HID + lane * 4);
    acc[0] += w * bf2f((unsigned short)v[0]);
    acc[1] += w * bf2f((unsigned short)v[1]);
    acc[2] += w * bf2f((unsigned short)v[2]);
    acc[3] += w * bf2f((unsigned short)v[3]);
  }

  const int col = lane * 4;
  short4v r;
#pragma unroll
  for (int j = 0; j < 4; ++j) {
    float v = acc[j] + b1[col + j];
    v = v > 0.0f ? v : 0.0f;
    unsigned o0, o1;
    threefry_0_42(0u, (unsigned)node * D_HID + col + j, o0, o1);
    const unsigned word = o0 ^ o1;
    r[j] = (word >> 31) ? (short)0 : f2bf(v * 2.0f);
  }
  *(short4v*)(h + (size_t)node * D_HID + col) = r;
}

// ---------------------------------------------------------------------------
// GEMM2 (bf16 MFMA): support2(f32)[100000,40] = h(bf16) @ W2
// ---------------------------------------------------------------------------
__global__ __launch_bounds__(256) void gemm2_mfma_kernel(const short* __restrict__ h,
                                                         const short* __restrict__ W2t,
                                                         float* __restrict__ out) {
  __shared__ __attribute__((aligned(16))) short As[128][40];
  __shared__ __attribute__((aligned(16))) short Bs[48][40];

  const int tid  = threadIdx.x;
  const int lane = tid & 63;
  const int wm   = tid >> 6;
  const int lr   = lane & 15;
  const int lg   = lane >> 4;
  const int row0 = blockIdx.x * 128;

  f32x4 acc[2][3] = {};

  for (int kt = 0; kt < D_HID; kt += 32) {
    {
#pragma unroll
      for (int c = 0; c < 2; ++c) {
        const int t2 = (tid << 1) | c;
        const int m  = t2 >> 2;
        const int kc = t2 & 3;
        const int grow = row0 + m;
        short8 v = (short8)0;
        if (grow < N_NODES)
          v = *(const short8*)(h + (size_t)grow * D_HID + kt + kc * 8);
        *(short8*)&As[m][kc * 8] = v;
      }
    }
    if (tid < 192) {
      const int n  = tid >> 2;
      const int kc = tid & 3;
      const short8 v = *(const short8*)(W2t + (size_t)n * D_HID + kt + kc * 8);
      *(short8*)&Bs[n][kc * 8] = v;
    }
    __syncthreads();

    short8 a[2], b[3];
#pragma unroll
    for (int mi = 0; mi < 2; ++mi)
      a[mi] = *(const short8*)&As[wm * 32 + mi * 16 + lr][lg * 8];
#pragma unroll
    for (int nj = 0; nj < 3; ++nj)
      b[nj] = *(const short8*)&Bs[nj * 16 + lr][lg * 8];

#pragma unroll
    for (int mi = 0; mi < 2; ++mi)
#pragma unroll
      for (int nj = 0; nj < 3; ++nj)
        acc[mi][nj] = __builtin_amdgcn_mfma_f32_16x16x32_bf16(a[mi], b[nj], acc[mi][nj], 0, 0, 0);

    __syncthreads();
  }

#pragma unroll
  for (int mi = 0; mi < 2; ++mi) {
#pragma unroll
    for (int nj = 0; nj < 3; ++nj) {
      const int gcol = nj * 16 + lr;
      if (gcol < D_OUT) {
#pragma unroll
        for (int r = 0; r < 4; ++r) {
          const int grow = row0 + wm * 32 + mi * 16 + lg * 4 + r;
          if (grow < N_NODES) out[(size_t)grow * D_OUT + gcol] = acc[mi][nj][r];
        }
      }
    }
  }
}

// ---------------------------------------------------------------------------
// SpMM2 (CSR) + fused bias + log_softmax -> d_out
// ---------------------------------------------------------------------------
__global__ __launch_bounds__(256) void spmm2_csr_kernel(const float* __restrict__ sup2,
                                                        const int* __restrict__ rowptr,
                                                        const int* __restrict__ srcs,
                                                        const float* __restrict__ wts,
                                                        const float* __restrict__ b2,
                                                        float* __restrict__ out) {
  const int node = blockIdx.x * 4 + (threadIdx.x >> 6);
  const int lane = threadIdx.x & 63;
  if (node >= N_NODES) return;
  const int beg = rowptr[node];
  const int end = rowptr[node + 1];

  float acc = 0.0f;
  for (int e = beg; e < end; ++e) {
    const int s = srcs[e];
    const float w = wts[e];
    if (lane < D_OUT) acc += w * sup2[(size_t)s * D_OUT + lane];
  }

  float v = (lane < D_OUT) ? acc + b2[lane] : -INFINITY;
  float m = v;
#pragma unroll
  for (int off = 32; off > 0; off >>= 1) m = fmaxf(m, __shfl_xor(m, off, 64));
  float e = (lane < D_OUT) ? expf(v - m) : 0.0f;
  float s = e;
#pragma unroll
  for (int off = 32; off > 0; off >>= 1) s += __shfl_xor(s, off, 64);
  if (lane < D_OUT) out[(size_t)node * D_OUT + lane] = v - m - logf(s);
}

// ---------------------------------------------------------------------------
extern "C" void kernel_launch(void* const* d_in, const int* in_sizes, int n_in,
                              void* d_out, int out_size, void* d_ws, size_t ws_size,
                              hipStream_t stream) {
  const float* x    = (const float*)d_in[0];
  const int*   esrc = (const int*)d_in[1];
  const int*   edst = (const int*)d_in[2];
  const float* ew   = (const float*)d_in[3];
  const float* W1   = (const float*)d_in[4];
  const float* b1   = (const float*)d_in[5];
  const float* W2   = (const float*)d_in[6];
  const float* b2   = (const float*)d_in[7];
  float* out = (float*)d_out;

  float* ws = (float*)d_ws;
  short* support1 = (short*)ws;                  // 25,600,000 bf16 (51.2 MB)
  short* hbuf     = (short*)(ws + 12800000);     // 25,600,000 bf16 (51.2 MB)
  float* support2 = ws + 25600000;               //  4,000,000 f32  (16 MB)
  int*   srcs_s   = (int*)(ws + 29600000);       //  1,600,000 i
  float* ws_s     = ws + 31200000;               //  1,600,000 f
  int*   rowptr   = (int*)(ws + 32800000);       //    100,001 i
  int*   counts   = (int*)(ws + 32900008);       //    100,000 i
  int*   cursor   = (int*)(ws + 33000008);       //    100,000 i
  short* W1t      = (short*)(ws + 33100008);     //    131,072 bf16
  short* W2t      = (short*)(ws + 33165544);     //     12,288 bf16
  int*   bsums    = (int*)(ws + 33171688);       //        391 i
  int*   boffs    = bsums + 512;                 //        391 i

  hipMemsetAsync(counts, 0, N_NODES * sizeof(int), stream);

  // CSR build + weight prep
  hist_kernel<<<(N_EDGES + 255) / 256, 256, 0, stream>>>(edst, counts);
  w1t_kernel<<<(D_IN * D_HID + 255) / 256, 256, 0, stream>>>(W1, W1t);
  w2t_kernel<<<(48 * D_HID + 255) / 256, 256, 0, stream>>>(W2, W2t);
  block_sum_kernel<<<SCAN_BLOCKS, 256, 0, stream>>>(counts, bsums);
  bsum_scan_kernel<<<1, 512, 0, stream>>>(bsums, boffs);
  scan_apply_kernel<<<SCAN_BLOCKS, 256, 0, stream>>>(counts, boffs, rowptr, cursor);
  scatter_kernel<<<(N_EDGES + 255) / 256, 256, 0, stream>>>(esrc, edst, ew, cursor, srcs_s, ws_s);

  // layer 1
  gemm1_mfma_kernel<<<(N_NODES + 127) / 128, 512, 0, stream>>>(x, W1t, support1);
  spmm1_csr_kernel<<<(N_NODES + 3) / 4, 256, 0, stream>>>(support1, rowptr, srcs_s, ws_s, b1, hbuf);

  // layer 2
  gemm2_mfma_kernel<<<(N_NODES + 127) / 128, 256, 0, stream>>>(hbuf, W2t, support2);
  spmm2_csr_kernel<<<(N_NODES + 3) / 4, 256, 0, stream>>>(support2, rowptr, srcs_s, ws_s, b2, out);
}

// Round 8
// 573.220 us; speedup vs baseline: 10.6690x; 1.1278x over previous
//
#include <hip/hip_runtime.h>
#include <math.h>

#define N_NODES 100000
#define N_EDGES 1600000
#define D_IN 512
#define D_HID 256
#define D_OUT 40
#define SCAN_BLOCKS ((N_NODES + 255) / 256)   // 391

typedef short short8 __attribute__((ext_vector_type(8)));
typedef short short4v __attribute__((ext_vector_type(4)));
typedef float f32x4 __attribute__((ext_vector_type(4)));

// f32 -> bf16, round-to-nearest-even
static __device__ __forceinline__ short f2bf(float f) {
  unsigned u = __float_as_uint(f);
  u = (u + 0x7fffu + ((u >> 16) & 1u)) >> 16;
  return (short)u;
}
static __device__ __forceinline__ float bf2f(unsigned short h) {
  return __uint_as_float(((unsigned)h) << 16);
}

// ---------------------------------------------------------------------------
// Threefry-2x32, 20 rounds, key = (0, 42)
// ---------------------------------------------------------------------------
static __device__ __forceinline__ void threefry_0_42(unsigned x0, unsigned x1,
                                                     unsigned& o0, unsigned& o1) {
  const unsigned ks0 = 0u;
  const unsigned ks1 = 42u;
  const unsigned ks2 = 0u ^ 42u ^ 0x1BD11BDAu;
  x0 += ks0; x1 += ks1;
#define TF_R(r) { x0 += x1; x1 = (x1 << (r)) | (x1 >> (32 - (r))); x1 ^= x0; }
  TF_R(13) TF_R(15) TF_R(26) TF_R(6)
  x0 += ks1; x1 += ks2 + 1u;
  TF_R(17) TF_R(29) TF_R(16) TF_R(24)
  x0 += ks2; x1 += ks0 + 2u;
  TF_R(13) TF_R(15) TF_R(26) TF_R(6)
  x0 += ks0; x1 += ks1 + 3u;
  TF_R(17) TF_R(29) TF_R(16) TF_R(24)
  x0 += ks1; x1 += ks2 + 4u;
  TF_R(13) TF_R(15) TF_R(26) TF_R(6)
  x0 += ks2; x1 += ks0 + 5u;
#undef TF_R
  o0 = x0; o1 = x1;
}

// ---------------------------------------------------------------------------
// CSR build
// ---------------------------------------------------------------------------
__global__ __launch_bounds__(256) void hist_kernel(const int* __restrict__ edst,
                                                   int* __restrict__ counts) {
  const int e = blockIdx.x * 256 + threadIdx.x;
  if (e < N_EDGES) atomicAdd(&counts[edst[e]], 1);
}

__global__ __launch_bounds__(256) void block_sum_kernel(const int* __restrict__ counts,
                                                        int* __restrict__ bsums) {
  __shared__ int red[256];
  const int t = threadIdx.x;
  const int i = blockIdx.x * 256 + t;
  red[t] = (i < N_NODES) ? counts[i] : 0;
  __syncthreads();
#pragma unroll
  for (int off = 128; off > 0; off >>= 1) {
    if (t < off) red[t] += red[t + off];
    __syncthreads();
  }
  if (t == 0) bsums[blockIdx.x] = red[0];
}

__global__ __launch_bounds__(512) void bsum_scan_kernel(const int* __restrict__ bsums,
                                                        int* __restrict__ boffs) {
  __shared__ int tmp[512];
  const int t = threadIdx.x;
  const int v = (t < SCAN_BLOCKS) ? bsums[t] : 0;
  tmp[t] = v;
  __syncthreads();
  for (int off = 1; off < 512; off <<= 1) {
    const int add = (t >= off) ? tmp[t - off] : 0;
    __syncthreads();
    tmp[t] += add;
    __syncthreads();
  }
  if (t < SCAN_BLOCKS) boffs[t] = tmp[t] - v;
}

__global__ __launch_bounds__(256) void scan_apply_kernel(const int* __restrict__ counts,
                                                         const int* __restrict__ boffs,
                                                         int* __restrict__ rowptr,
                                                         int* __restrict__ cursor) {
  __shared__ int tmp[256];
  const int t = threadIdx.x;
  const int i = blockIdx.x * 256 + t;
  const int v = (i < N_NODES) ? counts[i] : 0;
  tmp[t] = v;
  __syncthreads();
  for (int off = 1; off < 256; off <<= 1) {
    const int add = (t >= off) ? tmp[t - off] : 0;
    __syncthreads();
    tmp[t] += add;
    __syncthreads();
  }
  const int excl = boffs[blockIdx.x] + tmp[t] - v;
  if (i < N_NODES) {
    rowptr[i] = excl;
    cursor[i] = excl;
    if (i == N_NODES - 1) rowptr[N_NODES] = excl + v;
  }
}

__global__ __launch_bounds__(256) void scatter_kernel(const int* __restrict__ esrc,
                                                      const int* __restrict__ edst,
                                                      const float* __restrict__ ew,
                                                      int* __restrict__ cursor,
                                                      int* __restrict__ srcs_s,
                                                      float* __restrict__ ws_s) {
  const int e = blockIdx.x * 256 + threadIdx.x;
  if (e >= N_EDGES) return;
  const int d = edst[e];
  const int pos = atomicAdd(&cursor[d], 1);
  srcs_s[pos] = esrc[e];
  ws_s[pos] = ew[e];
}

// ---------------------------------------------------------------------------
// W1 [512][256] f32 -> W1t [256][512] bf16
// ---------------------------------------------------------------------------
__global__ __launch_bounds__(256) void w1t_kernel(const float* __restrict__ W1,
                                                  short* __restrict__ W1t) {
  const int i = blockIdx.x * 256 + threadIdx.x;
  if (i >= D_IN * D_HID) return;
  const int n = i >> 9;
  const int k = i & 511;
  W1t[i] = f2bf(W1[(size_t)k * D_HID + n]);
}

// W2 [256][40] f32 -> W2t [48][256] bf16 (cols 40..47 zero)
__global__ __launch_bounds__(256) void w2t_kernel(const float* __restrict__ W2,
                                                  short* __restrict__ W2t) {
  const int i = blockIdx.x * 256 + threadIdx.x;
  if (i >= 48 * D_HID) return;
  const int n = i >> 8;
  const int k = i & 255;
  W2t[i] = (n < D_OUT) ? f2bf(W2[(size_t)k * D_OUT + n]) : (short)0;
}

// ---------------------------------------------------------------------------
// GEMM1 (bf16 MFMA): support1(bf16)[100000,256] = x @ W1
// BM=128, BN=256, BK=32, 512 threads (8 waves 2x4)
// ---------------------------------------------------------------------------
__global__ __launch_bounds__(512) void gemm1_mfma_kernel(const float* __restrict__ x,
                                                         const short* __restrict__ W1t,
                                                         short* __restrict__ out) {
  __shared__ __attribute__((aligned(16))) short As[128][40];
  __shared__ __attribute__((aligned(16))) short Bs[256][40];

  const int tid  = threadIdx.x;
  const int lane = tid & 63;
  const int wid  = tid >> 6;
  const int wm   = wid >> 2;
  const int wn   = wid & 3;
  const int lr   = lane & 15;
  const int lg   = lane >> 4;
  const int row0 = blockIdx.x * 128;

  f32x4 acc[4][4] = {};

  for (int kt = 0; kt < D_IN; kt += 32) {
    {
      const int m  = tid >> 2;
      const int kc = tid & 3;
      short8 v;
      const int grow = row0 + m;
      if (grow < N_NODES) {
        const float* src = x + (size_t)grow * D_IN + kt + kc * 8;
        const float4 f0 = *(const float4*)(src);
        const float4 f1 = *(const float4*)(src + 4);
        v[0] = f2bf(f0.x); v[1] = f2bf(f0.y); v[2] = f2bf(f0.z); v[3] = f2bf(f0.w);
        v[4] = f2bf(f1.x); v[5] = f2bf(f1.y); v[6] = f2bf(f1.z); v[7] = f2bf(f1.w);
      } else {
        v = (short8)0;
      }
      *(short8*)&As[m][kc * 8] = v;
    }
    {
#pragma unroll
      for (int c = 0; c < 2; ++c) {
        const int t2 = (tid << 1) | c;
        const int n  = t2 >> 2;
        const int kc = t2 & 3;
        const short8 v = *(const short8*)(W1t + (size_t)n * D_IN + kt + kc * 8);
        *(short8*)&Bs[n][kc * 8] = v;
      }
    }
    __syncthreads();

    short8 a[4], b[4];
#pragma unroll
    for (int mi = 0; mi < 4; ++mi)
      a[mi] = *(const short8*)&As[wm * 64 + mi * 16 + lr][lg * 8];
#pragma unroll
    for (int nj = 0; nj < 4; ++nj)
      b[nj] = *(const short8*)&Bs[wn * 64 + nj * 16 + lr][lg * 8];

#pragma unroll
    for (int mi = 0; mi < 4; ++mi)
#pragma unroll
      for (int nj = 0; nj < 4; ++nj)
        acc[mi][nj] = __builtin_amdgcn_mfma_f32_16x16x32_bf16(a[mi], b[nj], acc[mi][nj], 0, 0, 0);

    __syncthreads();
  }

#pragma unroll
  for (int mi = 0; mi < 4; ++mi) {
#pragma unroll
    for (int nj = 0; nj < 4; ++nj) {
      const int gcol = wn * 64 + nj * 16 + lr;
#pragma unroll
      for (int r = 0; r < 4; ++r) {
        const int grow = row0 + wm * 64 + mi * 16 + lg * 4 + r;
        if (grow < N_NODES) out[(size_t)grow * D_HID + gcol] = f2bf(acc[mi][nj][r]);
      }
    }
  }
}

// ---------------------------------------------------------------------------
// SpMM1 (CSR) + fused bias + ReLU + dropout; bf16 in/out, f32 accum.
// One wave per dst node, split into two 32-lane halves: half h processes
// edges beg+h, beg+h+2, ... with 16B/lane loads (32 lanes cover a 512B row).
// Halves merged with one shfl_xor(32) per accumulator at the end.
// ---------------------------------------------------------------------------
__global__ __launch_bounds__(256) void spmm1_csr_kernel(const short* __restrict__ sup,
                                                        const int* __restrict__ rowptr,
                                                        const int* __restrict__ srcs,
                                                        const float* __restrict__ wts,
                                                        const float* __restrict__ b1,
                                                        short* __restrict__ h) {
  const int node = blockIdx.x * 4 + (threadIdx.x >> 6);
  const int lane = threadIdx.x & 63;
  const int half = lane >> 5;          // 0 or 1
  const int hl   = lane & 31;          // lane within half
  if (node >= N_NODES) return;
  const int beg = rowptr[node];
  const int end = rowptr[node + 1];

  float acc[8] = {};

  // unrolled by 2: up to 2 gathers in flight per half (4 per wave)
  int e = beg + half;
  for (; e + 2 < end; e += 4) {
    const int   s0 = srcs[e];
    const int   s1 = srcs[e + 2];
    const float w0 = wts[e];
    const float w1 = wts[e + 2];
    const short8 v0 = *(const short8*)(sup + (size_t)s0 * D_HID + hl * 8);
    const short8 v1 = *(const short8*)(sup + (size_t)s1 * D_HID + hl * 8);
#pragma unroll
    for (int j = 0; j < 8; ++j) acc[j] += w0 * bf2f((unsigned short)v0[j]);
#pragma unroll
    for (int j = 0; j < 8; ++j) acc[j] += w1 * bf2f((unsigned short)v1[j]);
  }
  if (e < end) {
    const int   s0 = srcs[e];
    const float w0 = wts[e];
    const short8 v0 = *(const short8*)(sup + (size_t)s0 * D_HID + hl * 8);
#pragma unroll
    for (int j = 0; j < 8; ++j) acc[j] += w0 * bf2f((unsigned short)v0[j]);
  }

  // merge halves: both halves end with the full edge sum for feats hl*8..hl*8+7
#pragma unroll
  for (int j = 0; j < 8; ++j) acc[j] += __shfl_xor(acc[j], 32, 64);

  // epilogue: half 0 writes feats hl*8..+3, half 1 writes hl*8+4..+7
  const int col = hl * 8 + half * 4;
  short4v r;
#pragma unroll
  for (int j = 0; j < 4; ++j) {
    float v = acc[half * 4 + j] + b1[col + j];
    v = v > 0.0f ? v : 0.0f;
    unsigned o0, o1;
    threefry_0_42(0u, (unsigned)node * D_HID + col + j, o0, o1);
    const unsigned word = o0 ^ o1;
    r[j] = (word >> 31) ? (short)0 : f2bf(v * 2.0f);
  }
  *(short4v*)(h + (size_t)node * D_HID + col) = r;
}

// ---------------------------------------------------------------------------
// GEMM2 (bf16 MFMA): support2(f32)[100000,40] = h(bf16) @ W2
// ---------------------------------------------------------------------------
__global__ __launch_bounds__(256) void gemm2_mfma_kernel(const short* __restrict__ h,
                                                         const short* __restrict__ W2t,
                                                         float* __restrict__ out) {
  __shared__ __attribute__((aligned(16))) short As[128][40];
  __shared__ __attribute__((aligned(16))) short Bs[48][40];

  const int tid  = threadIdx.x;
  const int lane = tid & 63;
  const int wm   = tid >> 6;
  const int lr   = lane & 15;
  const int lg   = lane >> 4;
  const int row0 = blockIdx.x * 128;

  f32x4 acc[2][3] = {};

  for (int kt = 0; kt < D_HID; kt += 32) {
    {
#pragma unroll
      for (int c = 0; c < 2; ++c) {
        const int t2 = (tid << 1) | c;
        const int m  = t2 >> 2;
        const int kc = t2 & 3;
        const int grow = row0 + m;
        short8 v = (short8)0;
        if (grow < N_NODES)
          v = *(const short8*)(h + (size_t)grow * D_HID + kt + kc * 8);
        *(short8*)&As[m][kc * 8] = v;
      }
    }
    if (tid < 192) {
      const int n  = tid >> 2;
      const int kc = tid & 3;
      const short8 v = *(const short8*)(W2t + (size_t)n * D_HID + kt + kc * 8);
      *(short8*)&Bs[n][kc * 8] = v;
    }
    __syncthreads();

    short8 a[2], b[3];
#pragma unroll
    for (int mi = 0; mi < 2; ++mi)
      a[mi] = *(const short8*)&As[wm * 32 + mi * 16 + lr][lg * 8];
#pragma unroll
    for (int nj = 0; nj < 3; ++nj)
      b[nj] = *(const short8*)&Bs[nj * 16 + lr][lg * 8];

#pragma unroll
    for (int mi = 0; mi < 2; ++mi)
#pragma unroll
      for (int nj = 0; nj < 3; ++nj)
        acc[mi][nj] = __builtin_amdgcn_mfma_f32_16x16x32_bf16(a[mi], b[nj], acc[mi][nj], 0, 0, 0);

    __syncthreads();
  }

#pragma unroll
  for (int mi = 0; mi < 2; ++mi) {
#pragma unroll
    for (int nj = 0; nj < 3; ++nj) {
      const int gcol = nj * 16 + lr;
      if (gcol < D_OUT) {
#pragma unroll
        for (int r = 0; r < 4; ++r) {
          const int grow = row0 + wm * 32 + mi * 16 + lg * 4 + r;
          if (grow < N_NODES) out[(size_t)grow * D_OUT + gcol] = acc[mi][nj][r];
        }
      }
    }
  }
}

// ---------------------------------------------------------------------------
// SpMM2 (CSR) + fused bias + log_softmax -> d_out
// ---------------------------------------------------------------------------
__global__ __launch_bounds__(256) void spmm2_csr_kernel(const float* __restrict__ sup2,
                                                        const int* __restrict__ rowptr,
                                                        const int* __restrict__ srcs,
                                                        const float* __restrict__ wts,
                                                        const float* __restrict__ b2,
                                                        float* __restrict__ out) {
  const int node = blockIdx.x * 4 + (threadIdx.x >> 6);
  const int lane = threadIdx.x & 63;
  if (node >= N_NODES) return;
  const int beg = rowptr[node];
  const int end = rowptr[node + 1];

  float acc = 0.0f;
  for (int e = beg; e < end; ++e) {
    const int s = srcs[e];
    const float w = wts[e];
    if (lane < D_OUT) acc += w * sup2[(size_t)s * D_OUT + lane];
  }

  float v = (lane < D_OUT) ? acc + b2[lane] : -INFINITY;
  float m = v;
#pragma unroll
  for (int off = 32; off > 0; off >>= 1) m = fmaxf(m, __shfl_xor(m, off, 64));
  float e = (lane < D_OUT) ? expf(v - m) : 0.0f;
  float s = e;
#pragma unroll
  for (int off = 32; off > 0; off >>= 1) s += __shfl_xor(s, off, 64);
  if (lane < D_OUT) out[(size_t)node * D_OUT + lane] = v - m - logf(s);
}

// ---------------------------------------------------------------------------
extern "C" void kernel_launch(void* const* d_in, const int* in_sizes, int n_in,
                              void* d_out, int out_size, void* d_ws, size_t ws_size,
                              hipStream_t stream) {
  const float* x    = (const float*)d_in[0];
  const int*   esrc = (const int*)d_in[1];
  const int*   edst = (const int*)d_in[2];
  const float* ew   = (const float*)d_in[3];
  const float* W1   = (const float*)d_in[4];
  const float* b1   = (const float*)d_in[5];
  const float* W2   = (const float*)d_in[6];
  const float* b2   = (const float*)d_in[7];
  float* out = (float*)d_out;

  float* ws = (float*)d_ws;
  short* support1 = (short*)ws;                  // 25,600,000 bf16 (51.2 MB)
  short* hbuf     = (short*)(ws + 12800000);     // 25,600,000 bf16 (51.2 MB)
  float* support2 = ws + 25600000;               //  4,000,000 f32  (16 MB)
  int*   srcs_s   = (int*)(ws + 29600000);       //  1,600,000 i
  float* ws_s     = ws + 31200000;               //  1,600,000 f
  int*   rowptr   = (int*)(ws + 32800000);       //    100,001 i
  int*   counts   = (int*)(ws + 32900008);       //    100,000 i
  int*   cursor   = (int*)(ws + 33000008);       //    100,000 i
  short* W1t      = (short*)(ws + 33100008);     //    131,072 bf16
  short* W2t      = (short*)(ws + 33165544);     //     12,288 bf16
  int*   bsums    = (int*)(ws + 33171688);       //        391 i
  int*   boffs    = bsums + 512;                 //        391 i

  hipMemsetAsync(counts, 0, N_NODES * sizeof(int), stream);

  // CSR build + weight prep
  hist_kernel<<<(N_EDGES + 255) / 256, 256, 0, stream>>>(edst, counts);
  w1t_kernel<<<(D_IN * D_HID + 255) / 256, 256, 0, stream>>>(W1, W1t);
  w2t_kernel<<<(48 * D_HID + 255) / 256, 256, 0, stream>>>(W2, W2t);
  block_sum_kernel<<<SCAN_BLOCKS, 256, 0, stream>>>(counts, bsums);
  bsum_scan_kernel<<<1, 512, 0, stream>>>(bsums, boffs);
  scan_apply_kernel<<<SCAN_BLOCKS, 256, 0, stream>>>(counts, boffs, rowptr, cursor);
  scatter_kernel<<<(N_EDGES + 255) / 256, 256, 0, stream>>>(esrc, edst, ew, cursor, srcs_s, ws_s);

  // layer 1
  gemm1_mfma_kernel<<<(N_NODES + 127) / 128, 512, 0, stream>>>(x, W1t, support1);
  spmm1_csr_kernel<<<(N_NODES + 3) / 4, 256, 0, stream>>>(support1, rowptr, srcs_s, ws_s, b1, hbuf);

  // layer 2
  gemm2_mfma_kernel<<<(N_NODES + 127) / 128, 256, 0, stream>>>(hbuf, W2t, support2);
  spmm2_csr_kernel<<<(N_NODES + 3) / 4, 256, 0, stream>>>(support2, rowptr, srcs_s, ws_s, b2, out);
}

// Round 9
// 487.327 us; speedup vs baseline: 12.5494x; 1.1763x over previous
//
#include <hip/hip_runtime.h>
#include <math.h>

#define N_NODES 100000
#define N_EDGES 1600000
#define D_IN 512
#define D_HID 256
#define D_OUT 40
#define S2_LD 48   // padded support2 leading dim (192B = 3 cache lines)
#define SCAN_BLOCKS ((N_NODES + 255) / 256)   // 391

typedef short short8 __attribute__((ext_vector_type(8)));
typedef short short4v __attribute__((ext_vector_type(4)));
typedef float f32x4 __attribute__((ext_vector_type(4)));

// f32 -> bf16, round-to-nearest-even
static __device__ __forceinline__ short f2bf(float f) {
  unsigned u = __float_as_uint(f);
  u = (u + 0x7fffu + ((u >> 16) & 1u)) >> 16;
  return (short)u;
}
static __device__ __forceinline__ float bf2f(unsigned short h) {
  return __uint_as_float(((unsigned)h) << 16);
}

// ---------------------------------------------------------------------------
// Threefry-2x32, 20 rounds, key = (0, 42)
// ---------------------------------------------------------------------------
static __device__ __forceinline__ void threefry_0_42(unsigned x0, unsigned x1,
                                                     unsigned& o0, unsigned& o1) {
  const unsigned ks0 = 0u;
  const unsigned ks1 = 42u;
  const unsigned ks2 = 0u ^ 42u ^ 0x1BD11BDAu;
  x0 += ks0; x1 += ks1;
#define TF_R(r) { x0 += x1; x1 = (x1 << (r)) | (x1 >> (32 - (r))); x1 ^= x0; }
  TF_R(13) TF_R(15) TF_R(26) TF_R(6)
  x0 += ks1; x1 += ks2 + 1u;
  TF_R(17) TF_R(29) TF_R(16) TF_R(24)
  x0 += ks2; x1 += ks0 + 2u;
  TF_R(13) TF_R(15) TF_R(26) TF_R(6)
  x0 += ks0; x1 += ks1 + 3u;
  TF_R(17) TF_R(29) TF_R(16) TF_R(24)
  x0 += ks1; x1 += ks2 + 4u;
  TF_R(13) TF_R(15) TF_R(26) TF_R(6)
  x0 += ks2; x1 += ks0 + 5u;
#undef TF_R
  o0 = x0; o1 = x1;
}

// ---------------------------------------------------------------------------
// CSR build
// ---------------------------------------------------------------------------
__global__ __launch_bounds__(256) void hist_kernel(const int* __restrict__ edst,
                                                   int* __restrict__ counts) {
  const int e = blockIdx.x * 256 + threadIdx.x;
  if (e < N_EDGES) atomicAdd(&counts[edst[e]], 1);
}

__global__ __launch_bounds__(256) void block_sum_kernel(const int* __restrict__ counts,
                                                        int* __restrict__ bsums) {
  __shared__ int red[256];
  const int t = threadIdx.x;
  const int i = blockIdx.x * 256 + t;
  red[t] = (i < N_NODES) ? counts[i] : 0;
  __syncthreads();
#pragma unroll
  for (int off = 128; off > 0; off >>= 1) {
    if (t < off) red[t] += red[t + off];
    __syncthreads();
  }
  if (t == 0) bsums[blockIdx.x] = red[0];
}

__global__ __launch_bounds__(512) void bsum_scan_kernel(const int* __restrict__ bsums,
                                                        int* __restrict__ boffs) {
  __shared__ int tmp[512];
  const int t = threadIdx.x;
  const int v = (t < SCAN_BLOCKS) ? bsums[t] : 0;
  tmp[t] = v;
  __syncthreads();
  for (int off = 1; off < 512; off <<= 1) {
    const int add = (t >= off) ? tmp[t - off] : 0;
    __syncthreads();
    tmp[t] += add;
    __syncthreads();
  }
  if (t < SCAN_BLOCKS) boffs[t] = tmp[t] - v;
}

__global__ __launch_bounds__(256) void scan_apply_kernel(const int* __restrict__ counts,
                                                         const int* __restrict__ boffs,
                                                         int* __restrict__ rowptr,
                                                         int* __restrict__ cursor) {
  __shared__ int tmp[256];
  const int t = threadIdx.x;
  const int i = blockIdx.x * 256 + t;
  const int v = (i < N_NODES) ? counts[i] : 0;
  tmp[t] = v;
  __syncthreads();
  for (int off = 1; off < 256; off <<= 1) {
    const int add = (t >= off) ? tmp[t - off] : 0;
    __syncthreads();
    tmp[t] += add;
    __syncthreads();
  }
  const int excl = boffs[blockIdx.x] + tmp[t] - v;
  if (i < N_NODES) {
    rowptr[i] = excl;
    cursor[i] = excl;
    if (i == N_NODES - 1) rowptr[N_NODES] = excl + v;
  }
}

__global__ __launch_bounds__(256) void scatter_kernel(const int* __restrict__ esrc,
                                                      const int* __restrict__ edst,
                                                      const float* __restrict__ ew,
                                                      int* __restrict__ cursor,
                                                      int* __restrict__ srcs_s,
                                                      float* __restrict__ ws_s) {
  const int e = blockIdx.x * 256 + threadIdx.x;
  if (e >= N_EDGES) return;
  const int d = edst[e];
  const int pos = atomicAdd(&cursor[d], 1);
  srcs_s[pos] = esrc[e];
  ws_s[pos] = ew[e];
}

// ---------------------------------------------------------------------------
// W1 [512][256] f32 -> W1t [256][512] bf16
// ---------------------------------------------------------------------------
__global__ __launch_bounds__(256) void w1t_kernel(const float* __restrict__ W1,
                                                  short* __restrict__ W1t) {
  const int i = blockIdx.x * 256 + threadIdx.x;
  if (i >= D_IN * D_HID) return;
  const int n = i >> 9;
  const int k = i & 511;
  W1t[i] = f2bf(W1[(size_t)k * D_HID + n]);
}

// W2 [256][40] f32 -> W2t [48][256] bf16 (cols 40..47 zero)
__global__ __launch_bounds__(256) void w2t_kernel(const float* __restrict__ W2,
                                                  short* __restrict__ W2t) {
  const int i = blockIdx.x * 256 + threadIdx.x;
  if (i >= 48 * D_HID) return;
  const int n = i >> 8;
  const int k = i & 255;
  W2t[i] = (n < D_OUT) ? f2bf(W2[(size_t)k * D_OUT + n]) : (short)0;
}

// ---------------------------------------------------------------------------
// GEMM1 (bf16 MFMA): support1(bf16)[100000,256] = x @ W1
// BM=128, BN=256, BK=32, 512 threads (8 waves 2x4)
// ---------------------------------------------------------------------------
__global__ __launch_bounds__(512) void gemm1_mfma_kernel(const float* __restrict__ x,
                                                         const short* __restrict__ W1t,
                                                         short* __restrict__ out) {
  __shared__ __attribute__((aligned(16))) short As[128][40];
  __shared__ __attribute__((aligned(16))) short Bs[256][40];

  const int tid  = threadIdx.x;
  const int lane = tid & 63;
  const int wid  = tid >> 6;
  const int wm   = wid >> 2;
  const int wn   = wid & 3;
  const int lr   = lane & 15;
  const int lg   = lane >> 4;
  const int row0 = blockIdx.x * 128;

  f32x4 acc[4][4] = {};

  for (int kt = 0; kt < D_IN; kt += 32) {
    {
      const int m  = tid >> 2;
      const int kc = tid & 3;
      short8 v;
      const int grow = row0 + m;
      if (grow < N_NODES) {
        const float* src = x + (size_t)grow * D_IN + kt + kc * 8;
        const float4 f0 = *(const float4*)(src);
        const float4 f1 = *(const float4*)(src + 4);
        v[0] = f2bf(f0.x); v[1] = f2bf(f0.y); v[2] = f2bf(f0.z); v[3] = f2bf(f0.w);
        v[4] = f2bf(f1.x); v[5] = f2bf(f1.y); v[6] = f2bf(f1.z); v[7] = f2bf(f1.w);
      } else {
        v = (short8)0;
      }
      *(short8*)&As[m][kc * 8] = v;
    }
    {
#pragma unroll
      for (int c = 0; c < 2; ++c) {
        const int t2 = (tid << 1) | c;
        const int n  = t2 >> 2;
        const int kc = t2 & 3;
        const short8 v = *(const short8*)(W1t + (size_t)n * D_IN + kt + kc * 8);
        *(short8*)&Bs[n][kc * 8] = v;
      }
    }
    __syncthreads();

    short8 a[4], b[4];
#pragma unroll
    for (int mi = 0; mi < 4; ++mi)
      a[mi] = *(const short8*)&As[wm * 64 + mi * 16 + lr][lg * 8];
#pragma unroll
    for (int nj = 0; nj < 4; ++nj)
      b[nj] = *(const short8*)&Bs[wn * 64 + nj * 16 + lr][lg * 8];

#pragma unroll
    for (int mi = 0; mi < 4; ++mi)
#pragma unroll
      for (int nj = 0; nj < 4; ++nj)
        acc[mi][nj] = __builtin_amdgcn_mfma_f32_16x16x32_bf16(a[mi], b[nj], acc[mi][nj], 0, 0, 0);

    __syncthreads();
  }

#pragma unroll
  for (int mi = 0; mi < 4; ++mi) {
#pragma unroll
    for (int nj = 0; nj < 4; ++nj) {
      const int gcol = wn * 64 + nj * 16 + lr;
#pragma unroll
      for (int r = 0; r < 4; ++r) {
        const int grow = row0 + wm * 64 + mi * 16 + lg * 4 + r;
        if (grow < N_NODES) out[(size_t)grow * D_HID + gcol] = f2bf(acc[mi][nj][r]);
      }
    }
  }
}

// ---------------------------------------------------------------------------
// SpMM1 (CSR) + fused bias + ReLU + dropout; bf16 in/out, f32 accum.
// Wave split into two 32-lane halves, each half one edge, 16B/lane.
// ---------------------------------------------------------------------------
__global__ __launch_bounds__(256) void spmm1_csr_kernel(const short* __restrict__ sup,
                                                        const int* __restrict__ rowptr,
                                                        const int* __restrict__ srcs,
                                                        const float* __restrict__ wts,
                                                        const float* __restrict__ b1,
                                                        short* __restrict__ h) {
  const int node = blockIdx.x * 4 + (threadIdx.x >> 6);
  const int lane = threadIdx.x & 63;
  const int half = lane >> 5;
  const int hl   = lane & 31;
  if (node >= N_NODES) return;
  const int beg = rowptr[node];
  const int end = rowptr[node + 1];

  float acc[8] = {};

  int e = beg + half;
  for (; e + 2 < end; e += 4) {
    const int   s0 = srcs[e];
    const int   s1 = srcs[e + 2];
    const float w0 = wts[e];
    const float w1 = wts[e + 2];
    const short8 v0 = *(const short8*)(sup + (size_t)s0 * D_HID + hl * 8);
    const short8 v1 = *(const short8*)(sup + (size_t)s1 * D_HID + hl * 8);
#pragma unroll
    for (int j = 0; j < 8; ++j) acc[j] += w0 * bf2f((unsigned short)v0[j]);
#pragma unroll
    for (int j = 0; j < 8; ++j) acc[j] += w1 * bf2f((unsigned short)v1[j]);
  }
  if (e < end) {
    const int   s0 = srcs[e];
    const float w0 = wts[e];
    const short8 v0 = *(const short8*)(sup + (size_t)s0 * D_HID + hl * 8);
#pragma unroll
    for (int j = 0; j < 8; ++j) acc[j] += w0 * bf2f((unsigned short)v0[j]);
  }

#pragma unroll
  for (int j = 0; j < 8; ++j) acc[j] += __shfl_xor(acc[j], 32, 64);

  const int col = hl * 8 + half * 4;
  short4v r;
#pragma unroll
  for (int j = 0; j < 4; ++j) {
    float v = acc[half * 4 + j] + b1[col + j];
    v = v > 0.0f ? v : 0.0f;
    unsigned o0, o1;
    threefry_0_42(0u, (unsigned)node * D_HID + col + j, o0, o1);
    const unsigned word = o0 ^ o1;
    r[j] = (word >> 31) ? (short)0 : f2bf(v * 2.0f);
  }
  *(short4v*)(h + (size_t)node * D_HID + col) = r;
}

// ---------------------------------------------------------------------------
// GEMM2 (bf16 MFMA): support2(f32, stride S2_LD)[100000] = h(bf16) @ W2
// ---------------------------------------------------------------------------
__global__ __launch_bounds__(256) void gemm2_mfma_kernel(const short* __restrict__ h,
                                                         const short* __restrict__ W2t,
                                                         float* __restrict__ out) {
  __shared__ __attribute__((aligned(16))) short As[128][40];
  __shared__ __attribute__((aligned(16))) short Bs[48][40];

  const int tid  = threadIdx.x;
  const int lane = tid & 63;
  const int wm   = tid >> 6;
  const int lr   = lane & 15;
  const int lg   = lane >> 4;
  const int row0 = blockIdx.x * 128;

  f32x4 acc[2][3] = {};

  for (int kt = 0; kt < D_HID; kt += 32) {
    {
#pragma unroll
      for (int c = 0; c < 2; ++c) {
        const int t2 = (tid << 1) | c;
        const int m  = t2 >> 2;
        const int kc = t2 & 3;
        const int grow = row0 + m;
        short8 v = (short8)0;
        if (grow < N_NODES)
          v = *(const short8*)(h + (size_t)grow * D_HID + kt + kc * 8);
        *(short8*)&As[m][kc * 8] = v;
      }
    }
    if (tid < 192) {
      const int n  = tid >> 2;
      const int kc = tid & 3;
      const short8 v = *(const short8*)(W2t + (size_t)n * D_HID + kt + kc * 8);
      *(short8*)&Bs[n][kc * 8] = v;
    }
    __syncthreads();

    short8 a[2], b[3];
#pragma unroll
    for (int mi = 0; mi < 2; ++mi)
      a[mi] = *(const short8*)&As[wm * 32 + mi * 16 + lr][lg * 8];
#pragma unroll
    for (int nj = 0; nj < 3; ++nj)
      b[nj] = *(const short8*)&Bs[nj * 16 + lr][lg * 8];

#pragma unroll
    for (int mi = 0; mi < 2; ++mi)
#pragma unroll
      for (int nj = 0; nj < 3; ++nj)
        acc[mi][nj] = __builtin_amdgcn_mfma_f32_16x16x32_bf16(a[mi], b[nj], acc[mi][nj], 0, 0, 0);

    __syncthreads();
  }

#pragma unroll
  for (int mi = 0; mi < 2; ++mi) {
#pragma unroll
    for (int nj = 0; nj < 3; ++nj) {
      const int gcol = nj * 16 + lr;
      if (gcol < D_OUT) {
#pragma unroll
        for (int r = 0; r < 4; ++r) {
          const int grow = row0 + wm * 32 + mi * 16 + lg * 4 + r;
          if (grow < N_NODES) out[(size_t)grow * S2_LD + gcol] = acc[mi][nj][r];
        }
      }
    }
  }
}

// ---------------------------------------------------------------------------
// SpMM2 (CSR, stride S2_LD) + fused bias + log_softmax -> d_out
// Unrolled by 4 edges: 4 independent gathers in flight per wave.
// ---------------------------------------------------------------------------
__global__ __launch_bounds__(256) void spmm2_csr_kernel(const float* __restrict__ sup2,
                                                        const int* __restrict__ rowptr,
                                                        const int* __restrict__ srcs,
                                                        const float* __restrict__ wts,
                                                        const float* __restrict__ b2,
                                                        float* __restrict__ out) {
  const int node = blockIdx.x * 4 + (threadIdx.x >> 6);
  const int lane = threadIdx.x & 63;
  if (node >= N_NODES) return;
  const int beg = rowptr[node];
  const int end = rowptr[node + 1];
  const bool act = lane < D_OUT;

  float a0 = 0.f, a1 = 0.f, a2 = 0.f, a3 = 0.f;
  int e = beg;
  for (; e + 4 <= end; e += 4) {
    const int   s0 = srcs[e],     s1 = srcs[e + 1], s2 = srcs[e + 2], s3 = srcs[e + 3];
    const float w0 = wts[e],      w1 = wts[e + 1],  w2 = wts[e + 2],  w3 = wts[e + 3];
    if (act) {
      const float v0 = sup2[(size_t)s0 * S2_LD + lane];
      const float v1 = sup2[(size_t)s1 * S2_LD + lane];
      const float v2 = sup2[(size_t)s2 * S2_LD + lane];
      const float v3 = sup2[(size_t)s3 * S2_LD + lane];
      a0 += w0 * v0; a1 += w1 * v1; a2 += w2 * v2; a3 += w3 * v3;
    }
  }
  for (; e < end; ++e) {
    if (act) a0 += wts[e] * sup2[(size_t)srcs[e] * S2_LD + lane];
  }
  float acc = (a0 + a1) + (a2 + a3);

  float v = act ? acc + b2[lane] : -INFINITY;
  float m = v;
#pragma unroll
  for (int off = 32; off > 0; off >>= 1) m = fmaxf(m, __shfl_xor(m, off, 64));
  float ex = act ? expf(v - m) : 0.0f;
  float s = ex;
#pragma unroll
  for (int off = 32; off > 0; off >>= 1) s += __shfl_xor(s, off, 64);
  if (act) out[(size_t)node * D_OUT + lane] = v - m - logf(s);
}

// ---------------------------------------------------------------------------
extern "C" void kernel_launch(void* const* d_in, const int* in_sizes, int n_in,
                              void* d_out, int out_size, void* d_ws, size_t ws_size,
                              hipStream_t stream) {
  const float* x    = (const float*)d_in[0];
  const int*   esrc = (const int*)d_in[1];
  const int*   edst = (const int*)d_in[2];
  const float* ew   = (const float*)d_in[3];
  const float* W1   = (const float*)d_in[4];
  const float* b1   = (const float*)d_in[5];
  const float* W2   = (const float*)d_in[6];
  const float* b2   = (const float*)d_in[7];
  float* out = (float*)d_out;

  float* ws = (float*)d_ws;
  short* support1 = (short*)ws;                  // 25,600,000 bf16 (51.2 MB)
  short* hbuf     = (short*)(ws + 12800000);     // 25,600,000 bf16 (51.2 MB)
  float* support2 = ws + 25600000;               //  4,800,000 f32  (19.2 MB, stride 48)
  int*   srcs_s   = (int*)(ws + 30400000);       //  1,600,000 i
  float* ws_s     = ws + 32000000;               //  1,600,000 f
  int*   rowptr   = (int*)(ws + 33600000);       //    100,001 i
  int*   counts   = (int*)(ws + 33700008);       //    100,000 i
  int*   cursor   = (int*)(ws + 33800008);       //    100,000 i
  short* W1t      = (short*)(ws + 33900008);     //    131,072 bf16
  short* W2t      = (short*)(ws + 33965544);     //     12,288 bf16
  int*   bsums    = (int*)(ws + 33971688);       //        391 i
  int*   boffs    = bsums + 512;                 //        391 i

  hipMemsetAsync(counts, 0, N_NODES * sizeof(int), stream);

  // CSR build + weight prep
  hist_kernel<<<(N_EDGES + 255) / 256, 256, 0, stream>>>(edst, counts);
  w1t_kernel<<<(D_IN * D_HID + 255) / 256, 256, 0, stream>>>(W1, W1t);
  w2t_kernel<<<(48 * D_HID + 255) / 256, 256, 0, stream>>>(W2, W2t);
  block_sum_kernel<<<SCAN_BLOCKS, 256, 0, stream>>>(counts, bsums);
  bsum_scan_kernel<<<1, 512, 0, stream>>>(bsums, boffs);
  scan_apply_kernel<<<SCAN_BLOCKS, 256, 0, stream>>>(counts, boffs, rowptr, cursor);
  scatter_kernel<<<(N_EDGES + 255) / 256, 256, 0, stream>>>(esrc, edst, ew, cursor, srcs_s, ws_s);

  // layer 1
  gemm1_mfma_kernel<<<(N_NODES + 127) / 128, 512, 0, stream>>>(x, W1t, support1);
  spmm1_csr_kernel<<<(N_NODES + 3) / 4, 256, 0, stream>>>(support1, rowptr, srcs_s, ws_s, b1, hbuf);

  // layer 2
  gemm2_mfma_kernel<<<(N_NODES + 127) / 128, 256, 0, stream>>>(hbuf, W2t, support2);
  spmm2_csr_kernel<<<(N_NODES + 3) / 4, 256, 0, stream>>>(support2, rowptr, srcs_s, ws_s, b2, out);
}

// Round 10
// 473.170 us; speedup vs baseline: 12.9249x; 1.0299x over previous
//
#include <hip/hip_runtime.h>
#include <math.h>

#define N_NODES 100000
#define N_EDGES 1600000
#define D_IN 512
#define D_HID 256
#define D_OUT 40
#define S2_LD 48   // padded support2 leading dim (192B = 3 cache lines)
#define SCAN_BLOCKS ((N_NODES + 255) / 256)   // 391

typedef short short8 __attribute__((ext_vector_type(8)));
typedef short short4v __attribute__((ext_vector_type(4)));
typedef float f32x4 __attribute__((ext_vector_type(4)));

// f32 -> bf16, round-to-nearest-even
static __device__ __forceinline__ short f2bf(float f) {
  unsigned u = __float_as_uint(f);
  u = (u + 0x7fffu + ((u >> 16) & 1u)) >> 16;
  return (short)u;
}
static __device__ __forceinline__ float bf2f(unsigned short h) {
  return __uint_as_float(((unsigned)h) << 16);
}

// ---------------------------------------------------------------------------
// Threefry-2x32, 20 rounds, key = (0, 42)
// ---------------------------------------------------------------------------
static __device__ __forceinline__ void threefry_0_42(unsigned x0, unsigned x1,
                                                     unsigned& o0, unsigned& o1) {
  const unsigned ks0 = 0u;
  const unsigned ks1 = 42u;
  const unsigned ks2 = 0u ^ 42u ^ 0x1BD11BDAu;
  x0 += ks0; x1 += ks1;
#define TF_R(r) { x0 += x1; x1 = (x1 << (r)) | (x1 >> (32 - (r))); x1 ^= x0; }
  TF_R(13) TF_R(15) TF_R(26) TF_R(6)
  x0 += ks1; x1 += ks2 + 1u;
  TF_R(17) TF_R(29) TF_R(16) TF_R(24)
  x0 += ks2; x1 += ks0 + 2u;
  TF_R(13) TF_R(15) TF_R(26) TF_R(6)
  x0 += ks0; x1 += ks1 + 3u;
  TF_R(17) TF_R(29) TF_R(16) TF_R(24)
  x0 += ks1; x1 += ks2 + 4u;
  TF_R(13) TF_R(15) TF_R(26) TF_R(6)
  x0 += ks2; x1 += ks0 + 5u;
#undef TF_R
  o0 = x0; o1 = x1;
}

// ---------------------------------------------------------------------------
// CSR build
// ---------------------------------------------------------------------------
__global__ __launch_bounds__(256) void hist_kernel(const int* __restrict__ edst,
                                                   int* __restrict__ counts) {
  const int e = blockIdx.x * 256 + threadIdx.x;
  if (e < N_EDGES) atomicAdd(&counts[edst[e]], 1);
}

__global__ __launch_bounds__(256) void block_sum_kernel(const int* __restrict__ counts,
                                                        int* __restrict__ bsums) {
  __shared__ int red[256];
  const int t = threadIdx.x;
  const int i = blockIdx.x * 256 + t;
  red[t] = (i < N_NODES) ? counts[i] : 0;
  __syncthreads();
#pragma unroll
  for (int off = 128; off > 0; off >>= 1) {
    if (t < off) red[t] += red[t + off];
    __syncthreads();
  }
  if (t == 0) bsums[blockIdx.x] = red[0];
}

__global__ __launch_bounds__(512) void bsum_scan_kernel(const int* __restrict__ bsums,
                                                        int* __restrict__ boffs) {
  __shared__ int tmp[512];
  const int t = threadIdx.x;
  const int v = (t < SCAN_BLOCKS) ? bsums[t] : 0;
  tmp[t] = v;
  __syncthreads();
  for (int off = 1; off < 512; off <<= 1) {
    const int add = (t >= off) ? tmp[t - off] : 0;
    __syncthreads();
    tmp[t] += add;
    __syncthreads();
  }
  if (t < SCAN_BLOCKS) boffs[t] = tmp[t] - v;
}

__global__ __launch_bounds__(256) void scan_apply_kernel(const int* __restrict__ counts,
                                                         const int* __restrict__ boffs,
                                                         int* __restrict__ rowptr,
                                                         int* __restrict__ cursor) {
  __shared__ int tmp[256];
  const int t = threadIdx.x;
  const int i = blockIdx.x * 256 + t;
  const int v = (i < N_NODES) ? counts[i] : 0;
  tmp[t] = v;
  __syncthreads();
  for (int off = 1; off < 256; off <<= 1) {
    const int add = (t >= off) ? tmp[t - off] : 0;
    __syncthreads();
    tmp[t] += add;
    __syncthreads();
  }
  const int excl = boffs[blockIdx.x] + tmp[t] - v;
  if (i < N_NODES) {
    rowptr[i] = excl;
    cursor[i] = excl;
    if (i == N_NODES - 1) rowptr[N_NODES] = excl + v;
  }
}

// Scatter edges into dst-sorted (src, weight) pairs — one 8B store
__global__ __launch_bounds__(256) void scatter_kernel(const int* __restrict__ esrc,
                                                      const int* __restrict__ edst,
                                                      const float* __restrict__ ew,
                                                      int* __restrict__ cursor,
                                                      int2* __restrict__ pairs) {
  const int e = blockIdx.x * 256 + threadIdx.x;
  if (e >= N_EDGES) return;
  const int d = edst[e];
  const int pos = atomicAdd(&cursor[d], 1);
  int2 p;
  p.x = esrc[e];
  p.y = __float_as_int(ew[e]);
  pairs[pos] = p;
}

// ---------------------------------------------------------------------------
// W1 [512][256] f32 -> W1t [256][512] bf16
// ---------------------------------------------------------------------------
__global__ __launch_bounds__(256) void w1t_kernel(const float* __restrict__ W1,
                                                  short* __restrict__ W1t) {
  const int i = blockIdx.x * 256 + threadIdx.x;
  if (i >= D_IN * D_HID) return;
  const int n = i >> 9;
  const int k = i & 511;
  W1t[i] = f2bf(W1[(size_t)k * D_HID + n]);
}

// W2 [256][40] f32 -> W2t [48][256] bf16 (cols 40..47 zero)
__global__ __launch_bounds__(256) void w2t_kernel(const float* __restrict__ W2,
                                                  short* __restrict__ W2t) {
  const int i = blockIdx.x * 256 + threadIdx.x;
  if (i >= 48 * D_HID) return;
  const int n = i >> 8;
  const int k = i & 255;
  W2t[i] = (n < D_OUT) ? f2bf(W2[(size_t)k * D_OUT + n]) : (short)0;
}

// ---------------------------------------------------------------------------
// GEMM1 (bf16 MFMA): support1(bf16)[100000,256] = x @ W1
// BM=128, BN=256, BK=32, 512 threads (8 waves 2x4)
// ---------------------------------------------------------------------------
__global__ __launch_bounds__(512) void gemm1_mfma_kernel(const float* __restrict__ x,
                                                         const short* __restrict__ W1t,
                                                         short* __restrict__ out) {
  __shared__ __attribute__((aligned(16))) short As[128][40];
  __shared__ __attribute__((aligned(16))) short Bs[256][40];

  const int tid  = threadIdx.x;
  const int lane = tid & 63;
  const int wid  = tid >> 6;
  const int wm   = wid >> 2;
  const int wn   = wid & 3;
  const int lr   = lane & 15;
  const int lg   = lane >> 4;
  const int row0 = blockIdx.x * 128;

  f32x4 acc[4][4] = {};

  for (int kt = 0; kt < D_IN; kt += 32) {
    {
      const int m  = tid >> 2;
      const int kc = tid & 3;
      short8 v;
      const int grow = row0 + m;
      if (grow < N_NODES) {
        const float* src = x + (size_t)grow * D_IN + kt + kc * 8;
        const float4 f0 = *(const float4*)(src);
        const float4 f1 = *(const float4*)(src + 4);
        v[0] = f2bf(f0.x); v[1] = f2bf(f0.y); v[2] = f2bf(f0.z); v[3] = f2bf(f0.w);
        v[4] = f2bf(f1.x); v[5] = f2bf(f1.y); v[6] = f2bf(f1.z); v[7] = f2bf(f1.w);
      } else {
        v = (short8)0;
      }
      *(short8*)&As[m][kc * 8] = v;
    }
    {
#pragma unroll
      for (int c = 0; c < 2; ++c) {
        const int t2 = (tid << 1) | c;
        const int n  = t2 >> 2;
        const int kc = t2 & 3;
        const short8 v = *(const short8*)(W1t + (size_t)n * D_IN + kt + kc * 8);
        *(short8*)&Bs[n][kc * 8] = v;
      }
    }
    __syncthreads();

    short8 a[4], b[4];
#pragma unroll
    for (int mi = 0; mi < 4; ++mi)
      a[mi] = *(const short8*)&As[wm * 64 + mi * 16 + lr][lg * 8];
#pragma unroll
    for (int nj = 0; nj < 4; ++nj)
      b[nj] = *(const short8*)&Bs[wn * 64 + nj * 16 + lr][lg * 8];

#pragma unroll
    for (int mi = 0; mi < 4; ++mi)
#pragma unroll
      for (int nj = 0; nj < 4; ++nj)
        acc[mi][nj] = __builtin_amdgcn_mfma_f32_16x16x32_bf16(a[mi], b[nj], acc[mi][nj], 0, 0, 0);

    __syncthreads();
  }

#pragma unroll
  for (int mi = 0; mi < 4; ++mi) {
#pragma unroll
    for (int nj = 0; nj < 4; ++nj) {
      const int gcol = wn * 64 + nj * 16 + lr;
#pragma unroll
      for (int r = 0; r < 4; ++r) {
        const int grow = row0 + wm * 64 + mi * 16 + lg * 4 + r;
        if (grow < N_NODES) out[(size_t)grow * D_HID + gcol] = f2bf(acc[mi][nj][r]);
      }
    }
  }
}

// ---------------------------------------------------------------------------
// SpMM1 (CSR) + fused bias + ReLU + dropout; bf16 in/out, f32 accum.
// Wave = two 32-lane halves; half h walks edges beg+h, beg+h+2, ...
// Unroll 4 per half -> up to 8 gathers in flight per wave.
// ---------------------------------------------------------------------------
__global__ __launch_bounds__(256) void spmm1_csr_kernel(const short* __restrict__ sup,
                                                        const int* __restrict__ rowptr,
                                                        const int2* __restrict__ pairs,
                                                        const float* __restrict__ b1,
                                                        short* __restrict__ h) {
  const int node = blockIdx.x * 4 + (threadIdx.x >> 6);
  const int lane = threadIdx.x & 63;
  const int half = lane >> 5;
  const int hl   = lane & 31;
  if (node >= N_NODES) return;
  const int beg = rowptr[node];
  const int end = rowptr[node + 1];

  float acc[8] = {};

  int e = beg + half;
  for (; e + 6 < end; e += 8) {
    const int2 p0 = pairs[e];
    const int2 p1 = pairs[e + 2];
    const int2 p2 = pairs[e + 4];
    const int2 p3 = pairs[e + 6];
    const short8 v0 = *(const short8*)(sup + (size_t)p0.x * D_HID + hl * 8);
    const short8 v1 = *(const short8*)(sup + (size_t)p1.x * D_HID + hl * 8);
    const short8 v2 = *(const short8*)(sup + (size_t)p2.x * D_HID + hl * 8);
    const short8 v3 = *(const short8*)(sup + (size_t)p3.x * D_HID + hl * 8);
    const float w0 = __int_as_float(p0.y);
    const float w1 = __int_as_float(p1.y);
    const float w2 = __int_as_float(p2.y);
    const float w3 = __int_as_float(p3.y);
#pragma unroll
    for (int j = 0; j < 8; ++j) acc[j] += w0 * bf2f((unsigned short)v0[j]);
#pragma unroll
    for (int j = 0; j < 8; ++j) acc[j] += w1 * bf2f((unsigned short)v1[j]);
#pragma unroll
    for (int j = 0; j < 8; ++j) acc[j] += w2 * bf2f((unsigned short)v2[j]);
#pragma unroll
    for (int j = 0; j < 8; ++j) acc[j] += w3 * bf2f((unsigned short)v3[j]);
  }
  for (; e < end; e += 2) {
    const int2 p0 = pairs[e];
    const float w0 = __int_as_float(p0.y);
    const short8 v0 = *(const short8*)(sup + (size_t)p0.x * D_HID + hl * 8);
#pragma unroll
    for (int j = 0; j < 8; ++j) acc[j] += w0 * bf2f((unsigned short)v0[j]);
  }

  // merge halves
#pragma unroll
  for (int j = 0; j < 8; ++j) acc[j] += __shfl_xor(acc[j], 32, 64);

  // epilogue: half 0 writes feats hl*8..+3, half 1 writes hl*8+4..+7
  const int col = hl * 8 + half * 4;
  short4v r;
#pragma unroll
  for (int j = 0; j < 4; ++j) {
    float v = acc[half * 4 + j] + b1[col + j];
    v = v > 0.0f ? v : 0.0f;
    unsigned o0, o1;
    threefry_0_42(0u, (unsigned)node * D_HID + col + j, o0, o1);
    const unsigned word = o0 ^ o1;
    r[j] = (word >> 31) ? (short)0 : f2bf(v * 2.0f);
  }
  *(short4v*)(h + (size_t)node * D_HID + col) = r;
}

// ---------------------------------------------------------------------------
// GEMM2 (bf16 MFMA): support2(f32, stride S2_LD)[100000] = h(bf16) @ W2
// ---------------------------------------------------------------------------
__global__ __launch_bounds__(256) void gemm2_mfma_kernel(const short* __restrict__ h,
                                                         const short* __restrict__ W2t,
                                                         float* __restrict__ out) {
  __shared__ __attribute__((aligned(16))) short As[128][40];
  __shared__ __attribute__((aligned(16))) short Bs[48][40];

  const int tid  = threadIdx.x;
  const int lane = tid & 63;
  const int wm   = tid >> 6;
  const int lr   = lane & 15;
  const int lg   = lane >> 4;
  const int row0 = blockIdx.x * 128;

  f32x4 acc[2][3] = {};

  for (int kt = 0; kt < D_HID; kt += 32) {
    {
#pragma unroll
      for (int c = 0; c < 2; ++c) {
        const int t2 = (tid << 1) | c;
        const int m  = t2 >> 2;
        const int kc = t2 & 3;
        const int grow = row0 + m;
        short8 v = (short8)0;
        if (grow < N_NODES)
          v = *(const short8*)(h + (size_t)grow * D_HID + kt + kc * 8);
        *(short8*)&As[m][kc * 8] = v;
      }
    }
    if (tid < 192) {
      const int n  = tid >> 2;
      const int kc = tid & 3;
      const short8 v = *(const short8*)(W2t + (size_t)n * D_HID + kt + kc * 8);
      *(short8*)&Bs[n][kc * 8] = v;
    }
    __syncthreads();

    short8 a[2], b[3];
#pragma unroll
    for (int mi = 0; mi < 2; ++mi)
      a[mi] = *(const short8*)&As[wm * 32 + mi * 16 + lr][lg * 8];
#pragma unroll
    for (int nj = 0; nj < 3; ++nj)
      b[nj] = *(const short8*)&Bs[nj * 16 + lr][lg * 8];

#pragma unroll
    for (int mi = 0; mi < 2; ++mi)
#pragma unroll
      for (int nj = 0; nj < 3; ++nj)
        acc[mi][nj] = __builtin_amdgcn_mfma_f32_16x16x32_bf16(a[mi], b[nj], acc[mi][nj], 0, 0, 0);

    __syncthreads();
  }

#pragma unroll
  for (int mi = 0; mi < 2; ++mi) {
#pragma unroll
    for (int nj = 0; nj < 3; ++nj) {
      const int gcol = nj * 16 + lr;
      if (gcol < D_OUT) {
#pragma unroll
        for (int r = 0; r < 4; ++r) {
          const int grow = row0 + wm * 32 + mi * 16 + lg * 4 + r;
          if (grow < N_NODES) out[(size_t)grow * S2_LD + gcol] = acc[mi][nj][r];
        }
      }
    }
  }
}

// ---------------------------------------------------------------------------
// SpMM2 (CSR, stride S2_LD) + fused bias + log_softmax -> d_out
// Unrolled by 4 edges: 4 independent gathers in flight per wave.
// ---------------------------------------------------------------------------
__global__ __launch_bounds__(256) void spmm2_csr_kernel(const float* __restrict__ sup2,
                                                        const int* __restrict__ rowptr,
                                                        const int2* __restrict__ pairs,
                                                        const float* __restrict__ b2,
                                                        float* __restrict__ out) {
  const int node = blockIdx.x * 4 + (threadIdx.x >> 6);
  const int lane = threadIdx.x & 63;
  if (node >= N_NODES) return;
  const int beg = rowptr[node];
  const int end = rowptr[node + 1];
  const bool act = lane < D_OUT;

  float a0 = 0.f, a1 = 0.f, a2 = 0.f, a3 = 0.f;
  int e = beg;
  for (; e + 4 <= end; e += 4) {
    const int2 p0 = pairs[e], p1 = pairs[e + 1], p2 = pairs[e + 2], p3 = pairs[e + 3];
    if (act) {
      const float v0 = sup2[(size_t)p0.x * S2_LD + lane];
      const float v1 = sup2[(size_t)p1.x * S2_LD + lane];
      const float v2 = sup2[(size_t)p2.x * S2_LD + lane];
      const float v3 = sup2[(size_t)p3.x * S2_LD + lane];
      a0 += __int_as_float(p0.y) * v0;
      a1 += __int_as_float(p1.y) * v1;
      a2 += __int_as_float(p2.y) * v2;
      a3 += __int_as_float(p3.y) * v3;
    }
  }
  for (; e < end; ++e) {
    const int2 p0 = pairs[e];
    if (act) a0 += __int_as_float(p0.y) * sup2[(size_t)p0.x * S2_LD + lane];
  }
  float acc = (a0 + a1) + (a2 + a3);

  float v = act ? acc + b2[lane] : -INFINITY;
  float m = v;
#pragma unroll
  for (int off = 32; off > 0; off >>= 1) m = fmaxf(m, __shfl_xor(m, off, 64));
  float ex = act ? expf(v - m) : 0.0f;
  float s = ex;
#pragma unroll
  for (int off = 32; off > 0; off >>= 1) s += __shfl_xor(s, off, 64);
  if (act) out[(size_t)node * D_OUT + lane] = v - m - logf(s);
}

// ---------------------------------------------------------------------------
extern "C" void kernel_launch(void* const* d_in, const int* in_sizes, int n_in,
                              void* d_out, int out_size, void* d_ws, size_t ws_size,
                              hipStream_t stream) {
  const float* x    = (const float*)d_in[0];
  const int*   esrc = (const int*)d_in[1];
  const int*   edst = (const int*)d_in[2];
  const float* ew   = (const float*)d_in[3];
  const float* W1   = (const float*)d_in[4];
  const float* b1   = (const float*)d_in[5];
  const float* W2   = (const float*)d_in[6];
  const float* b2   = (const float*)d_in[7];
  float* out = (float*)d_out;

  float* ws = (float*)d_ws;
  short* support1 = (short*)ws;                  // 25,600,000 bf16 (51.2 MB)
  short* hbuf     = (short*)(ws + 12800000);     // 25,600,000 bf16 (51.2 MB)
  float* support2 = ws + 25600000;               //  4,800,000 f32  (19.2 MB, stride 48)
  int2*  pairs    = (int2*)(ws + 30400000);      //  1,600,000 int2 (12.8 MB)
  int*   rowptr   = (int*)(ws + 33600000);       //    100,001 i
  int*   counts   = (int*)(ws + 33700008);       //    100,000 i
  int*   cursor   = (int*)(ws + 33800008);       //    100,000 i
  short* W1t      = (short*)(ws + 33900008);     //    131,072 bf16
  short* W2t      = (short*)(ws + 33965544);     //     12,288 bf16
  int*   bsums    = (int*)(ws + 33971688);       //        391 i
  int*   boffs    = bsums + 512;                 //        391 i

  hipMemsetAsync(counts, 0, N_NODES * sizeof(int), stream);

  // CSR build + weight prep
  hist_kernel<<<(N_EDGES + 255) / 256, 256, 0, stream>>>(edst, counts);
  w1t_kernel<<<(D_IN * D_HID + 255) / 256, 256, 0, stream>>>(W1, W1t);
  w2t_kernel<<<(48 * D_HID + 255) / 256, 256, 0, stream>>>(W2, W2t);
  block_sum_kernel<<<SCAN_BLOCKS, 256, 0, stream>>>(counts, bsums);
  bsum_scan_kernel<<<1, 512, 0, stream>>>(bsums, boffs);
  scan_apply_kernel<<<SCAN_BLOCKS, 256, 0, stream>>>(counts, boffs, rowptr, cursor);
  scatter_kernel<<<(N_EDGES + 255) / 256, 256, 0, stream>>>(esrc, edst, ew, cursor, pairs);

  // layer 1
  gemm1_mfma_kernel<<<(N_NODES + 127) / 128, 512, 0, stream>>>(x, W1t, support1);
  spmm1_csr_kernel<<<(N_NODES + 3) / 4, 256, 0, stream>>>(support1, rowptr, pairs, b1, hbuf);

  // layer 2
  gemm2_mfma_kernel<<<(N_NODES + 127) / 128, 256, 0, stream>>>(hbuf, W2t, support2);
  spmm2_csr_kernel<<<(N_NODES + 3) / 4, 256, 0, stream>>>(support2, rowptr, pairs, b2, out);
}

// Round 11
// 451.576 us; speedup vs baseline: 13.5429x; 1.0478x over previous
//
#include <hip/hip_runtime.h>
#include <math.h>

#define N_NODES 100000
#define N_EDGES 1600000
#define D_IN 512
#define D_HID 256
#define D_OUT 40
#define S2_LD 48   // support2 leading dim in bf16 elements (96B rows)
#define SCAN_BLOCKS ((N_NODES + 255) / 256)   // 391

typedef short short8 __attribute__((ext_vector_type(8)));
typedef short short4v __attribute__((ext_vector_type(4)));
typedef float f32x4 __attribute__((ext_vector_type(4)));

// f32 -> bf16, round-to-nearest-even
static __device__ __forceinline__ short f2bf(float f) {
  unsigned u = __float_as_uint(f);
  u = (u + 0x7fffu + ((u >> 16) & 1u)) >> 16;
  return (short)u;
}
static __device__ __forceinline__ float bf2f(unsigned short h) {
  return __uint_as_float(((unsigned)h) << 16);
}

// ---------------------------------------------------------------------------
// Threefry-2x32, 20 rounds, key = (0, 42)
// ---------------------------------------------------------------------------
static __device__ __forceinline__ void threefry_0_42(unsigned x0, unsigned x1,
                                                     unsigned& o0, unsigned& o1) {
  const unsigned ks0 = 0u;
  const unsigned ks1 = 42u;
  const unsigned ks2 = 0u ^ 42u ^ 0x1BD11BDAu;
  x0 += ks0; x1 += ks1;
#define TF_R(r) { x0 += x1; x1 = (x1 << (r)) | (x1 >> (32 - (r))); x1 ^= x0; }
  TF_R(13) TF_R(15) TF_R(26) TF_R(6)
  x0 += ks1; x1 += ks2 + 1u;
  TF_R(17) TF_R(29) TF_R(16) TF_R(24)
  x0 += ks2; x1 += ks0 + 2u;
  TF_R(13) TF_R(15) TF_R(26) TF_R(6)
  x0 += ks0; x1 += ks1 + 3u;
  TF_R(17) TF_R(29) TF_R(16) TF_R(24)
  x0 += ks1; x1 += ks2 + 4u;
  TF_R(13) TF_R(15) TF_R(26) TF_R(6)
  x0 += ks2; x1 += ks0 + 5u;
#undef TF_R
  o0 = x0; o1 = x1;
}

// ---------------------------------------------------------------------------
// CSR build
// ---------------------------------------------------------------------------
__global__ __launch_bounds__(256) void hist_kernel(const int* __restrict__ edst,
                                                   int* __restrict__ counts) {
  const int e = blockIdx.x * 256 + threadIdx.x;
  if (e < N_EDGES) atomicAdd(&counts[edst[e]], 1);
}

__global__ __launch_bounds__(256) void block_sum_kernel(const int* __restrict__ counts,
                                                        int* __restrict__ bsums) {
  __shared__ int red[256];
  const int t = threadIdx.x;
  const int i = blockIdx.x * 256 + t;
  red[t] = (i < N_NODES) ? counts[i] : 0;
  __syncthreads();
#pragma unroll
  for (int off = 128; off > 0; off >>= 1) {
    if (t < off) red[t] += red[t + off];
    __syncthreads();
  }
  if (t == 0) bsums[blockIdx.x] = red[0];
}

__global__ __launch_bounds__(512) void bsum_scan_kernel(const int* __restrict__ bsums,
                                                        int* __restrict__ boffs) {
  __shared__ int tmp[512];
  const int t = threadIdx.x;
  const int v = (t < SCAN_BLOCKS) ? bsums[t] : 0;
  tmp[t] = v;
  __syncthreads();
  for (int off = 1; off < 512; off <<= 1) {
    const int add = (t >= off) ? tmp[t - off] : 0;
    __syncthreads();
    tmp[t] += add;
    __syncthreads();
  }
  if (t < SCAN_BLOCKS) boffs[t] = tmp[t] - v;
}

__global__ __launch_bounds__(256) void scan_apply_kernel(const int* __restrict__ counts,
                                                         const int* __restrict__ boffs,
                                                         int* __restrict__ rowptr,
                                                         int* __restrict__ cursor) {
  __shared__ int tmp[256];
  const int t = threadIdx.x;
  const int i = blockIdx.x * 256 + t;
  const int v = (i < N_NODES) ? counts[i] : 0;
  tmp[t] = v;
  __syncthreads();
  for (int off = 1; off < 256; off <<= 1) {
    const int add = (t >= off) ? tmp[t - off] : 0;
    __syncthreads();
    tmp[t] += add;
    __syncthreads();
  }
  const int excl = boffs[blockIdx.x] + tmp[t] - v;
  if (i < N_NODES) {
    rowptr[i] = excl;
    cursor[i] = excl;
    if (i == N_NODES - 1) rowptr[N_NODES] = excl + v;
  }
}

// Scatter edges into dst-sorted (src, weight) pairs — one 8B store
__global__ __launch_bounds__(256) void scatter_kernel(const int* __restrict__ esrc,
                                                      const int* __restrict__ edst,
                                                      const float* __restrict__ ew,
                                                      int* __restrict__ cursor,
                                                      int2* __restrict__ pairs) {
  const int e = blockIdx.x * 256 + threadIdx.x;
  if (e >= N_EDGES) return;
  const int d = edst[e];
  const int pos = atomicAdd(&cursor[d], 1);
  int2 p;
  p.x = esrc[e];
  p.y = __float_as_int(ew[e]);
  pairs[pos] = p;
}

// ---------------------------------------------------------------------------
// Weight prep: W1t [256][512] bf16 (transpose) ; W2t [48][256] bf16 (pad)
// ---------------------------------------------------------------------------
__global__ __launch_bounds__(256) void wprep_kernel(const float* __restrict__ W1,
                                                    const float* __restrict__ W2,
                                                    short* __restrict__ W1t,
                                                    short* __restrict__ W2t) {
  const int i = blockIdx.x * 256 + threadIdx.x;
  if (i < D_IN * D_HID) {
    const int n = i >> 9;
    const int k = i & 511;
    W1t[i] = f2bf(W1[(size_t)k * D_HID + n]);
  } else {
    const int j = i - D_IN * D_HID;
    if (j < 48 * D_HID) {
      const int n = j >> 8;
      const int k = j & 255;
      W2t[j] = (n < D_OUT) ? f2bf(W2[(size_t)k * D_OUT + n]) : (short)0;
    }
  }
}

// ---------------------------------------------------------------------------
// GEMM1 (bf16 MFMA): support1(bf16)[100000,256] = x @ W1
// BM=128, BN=256, BK=32, 512 threads (8 waves 2x4)
// ---------------------------------------------------------------------------
__global__ __launch_bounds__(512) void gemm1_mfma_kernel(const float* __restrict__ x,
                                                         const short* __restrict__ W1t,
                                                         short* __restrict__ out) {
  __shared__ __attribute__((aligned(16))) short As[128][40];
  __shared__ __attribute__((aligned(16))) short Bs[256][40];

  const int tid  = threadIdx.x;
  const int lane = tid & 63;
  const int wid  = tid >> 6;
  const int wm   = wid >> 2;
  const int wn   = wid & 3;
  const int lr   = lane & 15;
  const int lg   = lane >> 4;
  const int row0 = blockIdx.x * 128;

  f32x4 acc[4][4] = {};

  for (int kt = 0; kt < D_IN; kt += 32) {
    {
      const int m  = tid >> 2;
      const int kc = tid & 3;
      short8 v;
      const int grow = row0 + m;
      if (grow < N_NODES) {
        const float* src = x + (size_t)grow * D_IN + kt + kc * 8;
        const float4 f0 = *(const float4*)(src);
        const float4 f1 = *(const float4*)(src + 4);
        v[0] = f2bf(f0.x); v[1] = f2bf(f0.y); v[2] = f2bf(f0.z); v[3] = f2bf(f0.w);
        v[4] = f2bf(f1.x); v[5] = f2bf(f1.y); v[6] = f2bf(f1.z); v[7] = f2bf(f1.w);
      } else {
        v = (short8)0;
      }
      *(short8*)&As[m][kc * 8] = v;
    }
    {
#pragma unroll
      for (int c = 0; c < 2; ++c) {
        const int t2 = (tid << 1) | c;
        const int n  = t2 >> 2;
        const int kc = t2 & 3;
        const short8 v = *(const short8*)(W1t + (size_t)n * D_IN + kt + kc * 8);
        *(short8*)&Bs[n][kc * 8] = v;
      }
    }
    __syncthreads();

    short8 a[4], b[4];
#pragma unroll
    for (int mi = 0; mi < 4; ++mi)
      a[mi] = *(const short8*)&As[wm * 64 + mi * 16 + lr][lg * 8];
#pragma unroll
    for (int nj = 0; nj < 4; ++nj)
      b[nj] = *(const short8*)&Bs[wn * 64 + nj * 16 + lr][lg * 8];

#pragma unroll
    for (int mi = 0; mi < 4; ++mi)
#pragma unroll
      for (int nj = 0; nj < 4; ++nj)
        acc[mi][nj] = __builtin_amdgcn_mfma_f32_16x16x32_bf16(a[mi], b[nj], acc[mi][nj], 0, 0, 0);

    __syncthreads();
  }

#pragma unroll
  for (int mi = 0; mi < 4; ++mi) {
#pragma unroll
    for (int nj = 0; nj < 4; ++nj) {
      const int gcol = wn * 64 + nj * 16 + lr;
#pragma unroll
      for (int r = 0; r < 4; ++r) {
        const int grow = row0 + wm * 64 + mi * 16 + lg * 4 + r;
        if (grow < N_NODES) out[(size_t)grow * D_HID + gcol] = f2bf(acc[mi][nj][r]);
      }
    }
  }
}

// ---------------------------------------------------------------------------
// SpMM1 (CSR) + fused bias + ReLU + dropout; bf16 in/out, f32 accum.
// Wave = two 32-lane halves; half h walks edges beg+h, beg+h+2, ...
// ---------------------------------------------------------------------------
__global__ __launch_bounds__(256) void spmm1_csr_kernel(const short* __restrict__ sup,
                                                        const int* __restrict__ rowptr,
                                                        const int2* __restrict__ pairs,
                                                        const float* __restrict__ b1,
                                                        short* __restrict__ h) {
  const int node = blockIdx.x * 4 + (threadIdx.x >> 6);
  const int lane = threadIdx.x & 63;
  const int half = lane >> 5;
  const int hl   = lane & 31;
  if (node >= N_NODES) return;
  const int beg = rowptr[node];
  const int end = rowptr[node + 1];

  float acc[8] = {};

  int e = beg + half;
  for (; e + 6 < end; e += 8) {
    const int2 p0 = pairs[e];
    const int2 p1 = pairs[e + 2];
    const int2 p2 = pairs[e + 4];
    const int2 p3 = pairs[e + 6];
    const short8 v0 = *(const short8*)(sup + (size_t)p0.x * D_HID + hl * 8);
    const short8 v1 = *(const short8*)(sup + (size_t)p1.x * D_HID + hl * 8);
    const short8 v2 = *(const short8*)(sup + (size_t)p2.x * D_HID + hl * 8);
    const short8 v3 = *(const short8*)(sup + (size_t)p3.x * D_HID + hl * 8);
    const float w0 = __int_as_float(p0.y);
    const float w1 = __int_as_float(p1.y);
    const float w2 = __int_as_float(p2.y);
    const float w3 = __int_as_float(p3.y);
#pragma unroll
    for (int j = 0; j < 8; ++j) acc[j] += w0 * bf2f((unsigned short)v0[j]);
#pragma unroll
    for (int j = 0; j < 8; ++j) acc[j] += w1 * bf2f((unsigned short)v1[j]);
#pragma unroll
    for (int j = 0; j < 8; ++j) acc[j] += w2 * bf2f((unsigned short)v2[j]);
#pragma unroll
    for (int j = 0; j < 8; ++j) acc[j] += w3 * bf2f((unsigned short)v3[j]);
  }
  for (; e < end; e += 2) {
    const int2 p0 = pairs[e];
    const float w0 = __int_as_float(p0.y);
    const short8 v0 = *(const short8*)(sup + (size_t)p0.x * D_HID + hl * 8);
#pragma unroll
    for (int j = 0; j < 8; ++j) acc[j] += w0 * bf2f((unsigned short)v0[j]);
  }

#pragma unroll
  for (int j = 0; j < 8; ++j) acc[j] += __shfl_xor(acc[j], 32, 64);

  const int col = hl * 8 + half * 4;
  short4v r;
#pragma unroll
  for (int j = 0; j < 4; ++j) {
    float v = acc[half * 4 + j] + b1[col + j];
    v = v > 0.0f ? v : 0.0f;
    unsigned o0, o1;
    threefry_0_42(0u, (unsigned)node * D_HID + col + j, o0, o1);
    const unsigned word = o0 ^ o1;
    r[j] = (word >> 31) ? (short)0 : f2bf(v * 2.0f);
  }
  *(short4v*)(h + (size_t)node * D_HID + col) = r;
}

// ---------------------------------------------------------------------------
// GEMM2 (bf16 MFMA): support2(bf16, stride S2_LD)[100000] = h(bf16) @ W2
// ---------------------------------------------------------------------------
__global__ __launch_bounds__(256) void gemm2_mfma_kernel(const short* __restrict__ h,
                                                         const short* __restrict__ W2t,
                                                         short* __restrict__ out) {
  __shared__ __attribute__((aligned(16))) short As[128][40];
  __shared__ __attribute__((aligned(16))) short Bs[48][40];

  const int tid  = threadIdx.x;
  const int lane = tid & 63;
  const int wm   = tid >> 6;
  const int lr   = lane & 15;
  const int lg   = lane >> 4;
  const int row0 = blockIdx.x * 128;

  f32x4 acc[2][3] = {};

  for (int kt = 0; kt < D_HID; kt += 32) {
    {
#pragma unroll
      for (int c = 0; c < 2; ++c) {
        const int t2 = (tid << 1) | c;
        const int m  = t2 >> 2;
        const int kc = t2 & 3;
        const int grow = row0 + m;
        short8 v = (short8)0;
        if (grow < N_NODES)
          v = *(const short8*)(h + (size_t)grow * D_HID + kt + kc * 8);
        *(short8*)&As[m][kc * 8] = v;
      }
    }
    if (tid < 192) {
      const int n  = tid >> 2;
      const int kc = tid & 3;
      const short8 v = *(const short8*)(W2t + (size_t)n * D_HID + kt + kc * 8);
      *(short8*)&Bs[n][kc * 8] = v;
    }
    __syncthreads();

    short8 a[2], b[3];
#pragma unroll
    for (int mi = 0; mi < 2; ++mi)
      a[mi] = *(const short8*)&As[wm * 32 + mi * 16 + lr][lg * 8];
#pragma unroll
    for (int nj = 0; nj < 3; ++nj)
      b[nj] = *(const short8*)&Bs[nj * 16 + lr][lg * 8];

#pragma unroll
    for (int mi = 0; mi < 2; ++mi)
#pragma unroll
      for (int nj = 0; nj < 3; ++nj)
        acc[mi][nj] = __builtin_amdgcn_mfma_f32_16x16x32_bf16(a[mi], b[nj], acc[mi][nj], 0, 0, 0);

    __syncthreads();
  }

#pragma unroll
  for (int mi = 0; mi < 2; ++mi) {
#pragma unroll
    for (int nj = 0; nj < 3; ++nj) {
      const int gcol = nj * 16 + lr;
      if (gcol < D_OUT) {
#pragma unroll
        for (int r = 0; r < 4; ++r) {
          const int grow = row0 + wm * 32 + mi * 16 + lg * 4 + r;
          if (grow < N_NODES) out[(size_t)grow * S2_LD + gcol] = f2bf(acc[mi][nj][r]);
        }
      }
    }
  }
}

// ---------------------------------------------------------------------------
// SpMM2 (CSR, bf16, stride S2_LD) + fused bias + log_softmax -> d_out
// Two nodes per wave: each 32-lane half owns one node; lanes 0..19 of the
// half each cover 2 feats (one uint = 2 bf16). Width-32 shuffles for softmax.
// ---------------------------------------------------------------------------
__global__ __launch_bounds__(256) void spmm2_csr_kernel(const short* __restrict__ sup2,
                                                        const int* __restrict__ rowptr,
                                                        const int2* __restrict__ pairs,
                                                        const float* __restrict__ b2,
                                                        float* __restrict__ out) {
  const int lane = threadIdx.x & 63;
  const int half = lane >> 5;
  const int hl   = lane & 31;
  const int node = blockIdx.x * 8 + ((threadIdx.x >> 6) << 1) + half;
  if (node >= N_NODES) return;
  const int beg = rowptr[node];
  const int end = rowptr[node + 1];
  const bool act = hl < 20;

  float a0 = 0.f, a1 = 0.f, b0 = 0.f, b1 = 0.f;
  float c0 = 0.f, c1 = 0.f, d0 = 0.f, d1 = 0.f;
  int e = beg;
  for (; e + 4 <= end; e += 4) {
    const int2 p0 = pairs[e], p1 = pairs[e + 1], p2 = pairs[e + 2], p3 = pairs[e + 3];
    if (act) {
      const unsigned u0 = *(const unsigned*)(sup2 + (size_t)p0.x * S2_LD + hl * 2);
      const unsigned u1 = *(const unsigned*)(sup2 + (size_t)p1.x * S2_LD + hl * 2);
      const unsigned u2 = *(const unsigned*)(sup2 + (size_t)p2.x * S2_LD + hl * 2);
      const unsigned u3 = *(const unsigned*)(sup2 + (size_t)p3.x * S2_LD + hl * 2);
      const float w0 = __int_as_float(p0.y);
      const float w1 = __int_as_float(p1.y);
      const float w2 = __int_as_float(p2.y);
      const float w3 = __int_as_float(p3.y);
      a0 += w0 * bf2f((unsigned short)(u0 & 0xffff)); a1 += w0 * bf2f((unsigned short)(u0 >> 16));
      b0 += w1 * bf2f((unsigned short)(u1 & 0xffff)); b1 += w1 * bf2f((unsigned short)(u1 >> 16));
      c0 += w2 * bf2f((unsigned short)(u2 & 0xffff)); c1 += w2 * bf2f((unsigned short)(u2 >> 16));
      d0 += w3 * bf2f((unsigned short)(u3 & 0xffff)); d1 += w3 * bf2f((unsigned short)(u3 >> 16));
    }
  }
  for (; e < end; ++e) {
    const int2 p0 = pairs[e];
    if (act) {
      const unsigned u0 = *(const unsigned*)(sup2 + (size_t)p0.x * S2_LD + hl * 2);
      const float w0 = __int_as_float(p0.y);
      a0 += w0 * bf2f((unsigned short)(u0 & 0xffff)); a1 += w0 * bf2f((unsigned short)(u0 >> 16));
    }
  }
  const float f0 = (a0 + b0) + (c0 + d0);
  const float f1 = (a1 + b1) + (c1 + d1);

  // bias + log_softmax over 40 classes within the 32-lane half
  const float v0 = act ? f0 + b2[hl * 2]     : -INFINITY;
  const float v1 = act ? f1 + b2[hl * 2 + 1] : -INFINITY;
  float m = fmaxf(v0, v1);
#pragma unroll
  for (int off = 16; off > 0; off >>= 1) m = fmaxf(m, __shfl_xor(m, off, 32));
  float s = act ? __expf(v0 - m) + __expf(v1 - m) : 0.0f;
#pragma unroll
  for (int off = 16; off > 0; off >>= 1) s += __shfl_xor(s, off, 32);
  if (act) {
    const float ls = logf(s);
    float2 r;
    r.x = v0 - m - ls;
    r.y = v1 - m - ls;
    *(float2*)&out[(size_t)node * D_OUT + hl * 2] = r;
  }
}

// ---------------------------------------------------------------------------
extern "C" void kernel_launch(void* const* d_in, const int* in_sizes, int n_in,
                              void* d_out, int out_size, void* d_ws, size_t ws_size,
                              hipStream_t stream) {
  const float* x    = (const float*)d_in[0];
  const int*   esrc = (const int*)d_in[1];
  const int*   edst = (const int*)d_in[2];
  const float* ew   = (const float*)d_in[3];
  const float* W1   = (const float*)d_in[4];
  const float* b1   = (const float*)d_in[5];
  const float* W2   = (const float*)d_in[6];
  const float* b2   = (const float*)d_in[7];
  float* out = (float*)d_out;

  float* ws = (float*)d_ws;
  short* support1 = (short*)ws;                  // 25,600,000 bf16 (51.2 MB)
  short* hbuf     = (short*)(ws + 12800000);     // 25,600,000 bf16 (51.2 MB)
  short* support2 = (short*)(ws + 25600000);     //  4,800,000 bf16 (9.6 MB, stride 48)
  int2*  pairs    = (int2*)(ws + 30400000);      //  1,600,000 int2 (12.8 MB)
  int*   rowptr   = (int*)(ws + 33600000);       //    100,001 i
  int*   counts   = (int*)(ws + 33700008);       //    100,000 i
  int*   cursor   = (int*)(ws + 33800008);       //    100,000 i
  short* W1t      = (short*)(ws + 33900008);     //    131,072 bf16
  short* W2t      = (short*)(ws + 33965544);     //     12,288 bf16
  int*   bsums    = (int*)(ws + 33971688);       //        391 i
  int*   boffs    = bsums + 512;                 //        391 i

  hipMemsetAsync(counts, 0, N_NODES * sizeof(int), stream);

  // CSR build + weight prep
  hist_kernel<<<(N_EDGES + 255) / 256, 256, 0, stream>>>(edst, counts);
  wprep_kernel<<<(D_IN * D_HID + 48 * D_HID + 255) / 256, 256, 0, stream>>>(W1, W2, W1t, W2t);
  block_sum_kernel<<<SCAN_BLOCKS, 256, 0, stream>>>(counts, bsums);
  bsum_scan_kernel<<<1, 512, 0, stream>>>(bsums, boffs);
  scan_apply_kernel<<<SCAN_BLOCKS, 256, 0, stream>>>(counts, boffs, rowptr, cursor);
  scatter_kernel<<<(N_EDGES + 255) / 256, 256, 0, stream>>>(esrc, edst, ew, cursor, pairs);

  // layer 1
  gemm1_mfma_kernel<<<(N_NODES + 127) / 128, 512, 0, stream>>>(x, W1t, support1);
  spmm1_csr_kernel<<<(N_NODES + 3) / 4, 256, 0, stream>>>(support1, rowptr, pairs, b1, hbuf);

  // layer 2
  gemm2_mfma_kernel<<<(N_NODES + 127) / 128, 256, 0, stream>>>(hbuf, W2t, support2);
  spmm2_csr_kernel<<<(N_NODES + 7) / 8, 256, 0, stream>>>(support2, rowptr, pairs, b2, out);
}

// Round 12
// 438.566 us; speedup vs baseline: 13.9447x; 1.0297x over previous
//
#include <hip/hip_runtime.h>
#include <hip/hip_bf16.h>
#include <math.h>

#define N_NODES 100000
#define N_EDGES 1600000
#define D_IN 512
#define D_HID 256
#define D_OUT 40
#define S2_LD 48   // support2 leading dim in bf16 elements (96B rows)
#define SCAN_BLOCKS ((N_NODES + 255) / 256)   // 391

#define G1_BLOCKS ((N_NODES + 127) / 128)          // 782
#define HIST_BLOCKS ((N_EDGES + 511) / 512)        // 3125
#define WPREP_N (D_IN * D_HID + 48 * D_HID)        // 143360
#define WPREP_BLOCKS ((WPREP_N + 511) / 512)       // 280

typedef short short8 __attribute__((ext_vector_type(8)));
typedef short short4v __attribute__((ext_vector_type(4)));
typedef float f32x4 __attribute__((ext_vector_type(4)));

// f32 -> bf16 via native cast (RNE); compiler emits v_cvt_pk_bf16_f32 pairs
static __device__ __forceinline__ short f2bf(float f) {
  union { __hip_bfloat16 b; short s; } u;
  u.b = __float2bfloat16(f);
  return u.s;
}
static __device__ __forceinline__ float bf2f(unsigned short h) {
  return __uint_as_float(((unsigned)h) << 16);
}

// ---------------------------------------------------------------------------
// Threefry-2x32, 20 rounds, key = (0, 42)
// ---------------------------------------------------------------------------
static __device__ __forceinline__ void threefry_0_42(unsigned x0, unsigned x1,
                                                     unsigned& o0, unsigned& o1) {
  const unsigned ks0 = 0u;
  const unsigned ks1 = 42u;
  const unsigned ks2 = 0u ^ 42u ^ 0x1BD11BDAu;
  x0 += ks0; x1 += ks1;
#define TF_R(r) { x0 += x1; x1 = (x1 << (r)) | (x1 >> (32 - (r))); x1 ^= x0; }
  TF_R(13) TF_R(15) TF_R(26) TF_R(6)
  x0 += ks1; x1 += ks2 + 1u;
  TF_R(17) TF_R(29) TF_R(16) TF_R(24)
  x0 += ks2; x1 += ks0 + 2u;
  TF_R(13) TF_R(15) TF_R(26) TF_R(6)
  x0 += ks0; x1 += ks1 + 3u;
  TF_R(17) TF_R(29) TF_R(16) TF_R(24)
  x0 += ks1; x1 += ks2 + 4u;
  TF_R(13) TF_R(15) TF_R(26) TF_R(6)
  x0 += ks2; x1 += ks0 + 5u;
#undef TF_R
  o0 = x0; o1 = x1;
}

// ---------------------------------------------------------------------------
// CSR build (scan stages)
// ---------------------------------------------------------------------------
__global__ __launch_bounds__(256) void block_sum_kernel(const int* __restrict__ counts,
                                                        int* __restrict__ bsums) {
  __shared__ int red[256];
  const int t = threadIdx.x;
  const int i = blockIdx.x * 256 + t;
  red[t] = (i < N_NODES) ? counts[i] : 0;
  __syncthreads();
#pragma unroll
  for (int off = 128; off > 0; off >>= 1) {
    if (t < off) red[t] += red[t + off];
    __syncthreads();
  }
  if (t == 0) bsums[blockIdx.x] = red[0];
}

__global__ __launch_bounds__(512) void bsum_scan_kernel(const int* __restrict__ bsums,
                                                        int* __restrict__ boffs) {
  __shared__ int tmp[512];
  const int t = threadIdx.x;
  const int v = (t < SCAN_BLOCKS) ? bsums[t] : 0;
  tmp[t] = v;
  __syncthreads();
  for (int off = 1; off < 512; off <<= 1) {
    const int add = (t >= off) ? tmp[t - off] : 0;
    __syncthreads();
    tmp[t] += add;
    __syncthreads();
  }
  if (t < SCAN_BLOCKS) boffs[t] = tmp[t] - v;
}

__global__ __launch_bounds__(256) void scan_apply_kernel(const int* __restrict__ counts,
                                                         const int* __restrict__ boffs,
                                                         int* __restrict__ rowptr,
                                                         int* __restrict__ cursor) {
  __shared__ int tmp[256];
  const int t = threadIdx.x;
  const int i = blockIdx.x * 256 + t;
  const int v = (i < N_NODES) ? counts[i] : 0;
  tmp[t] = v;
  __syncthreads();
  for (int off = 1; off < 256; off <<= 1) {
    const int add = (t >= off) ? tmp[t - off] : 0;
    __syncthreads();
    tmp[t] += add;
    __syncthreads();
  }
  const int excl = boffs[blockIdx.x] + tmp[t] - v;
  if (i < N_NODES) {
    rowptr[i] = excl;
    cursor[i] = excl;
    if (i == N_NODES - 1) rowptr[N_NODES] = excl + v;
  }
}

// Scatter edges into dst-sorted (src, weight) pairs — one 8B store
__global__ __launch_bounds__(256) void scatter_kernel(const int* __restrict__ esrc,
                                                      const int* __restrict__ edst,
                                                      const float* __restrict__ ew,
                                                      int* __restrict__ cursor,
                                                      int2* __restrict__ pairs) {
  const int e = blockIdx.x * 256 + threadIdx.x;
  if (e >= N_EDGES) return;
  const int d = edst[e];
  const int pos = atomicAdd(&cursor[d], 1);
  int2 p;
  p.x = esrc[e];
  p.y = __float_as_int(ew[e]);
  pairs[pos] = p;
}

// ---------------------------------------------------------------------------
// MERGED K1: gemm1 (blocks 0..781) + hist (next 3125) + wprep (next 280)
// gemm1: support1(bf16)[100000,256] = x @ W1 ; BM=128,BN=256,BK=32, 8 waves
// ---------------------------------------------------------------------------
__global__ __launch_bounds__(512) void k1_gemm1_hist_wprep_kernel(
    const float* __restrict__ x, const short* __restrict__ W1t,
    short* __restrict__ out,
    const int* __restrict__ edst, int* __restrict__ counts,
    const float* __restrict__ W1, const float* __restrict__ W2,
    short* __restrict__ W1t_out, short* __restrict__ W2t_out) {
  const int bid = blockIdx.x;
  const int tid = threadIdx.x;

  if (bid >= G1_BLOCKS) {
    const int xb = bid - G1_BLOCKS;
    if (xb < HIST_BLOCKS) {
      // histogram of edge_dst
      const int e = xb * 512 + tid;
      if (e < N_EDGES) atomicAdd(&counts[edst[e]], 1);
    } else {
      // weight prep: W1t [256][512] bf16 (transpose), W2t [48][256] bf16 (pad)
      const int i = (xb - HIST_BLOCKS) * 512 + tid;
      if (i < D_IN * D_HID) {
        const int n = i >> 9;
        const int k = i & 511;
        W1t_out[i] = f2bf(W1[(size_t)k * D_HID + n]);
      } else if (i < WPREP_N) {
        const int j = i - D_IN * D_HID;
        const int n = j >> 8;
        const int k = j & 255;
        W2t_out[j] = (n < D_OUT) ? f2bf(W2[(size_t)k * D_OUT + n]) : (short)0;
      }
    }
    return;
  }

  __shared__ __attribute__((aligned(16))) short As[128][40];
  __shared__ __attribute__((aligned(16))) short Bs[256][40];

  const int lane = tid & 63;
  const int wid  = tid >> 6;
  const int wm   = wid >> 2;
  const int wn   = wid & 3;
  const int lr   = lane & 15;
  const int lg   = lane >> 4;
  const int row0 = bid * 128;

  f32x4 acc[4][4] = {};

  for (int kt = 0; kt < D_IN; kt += 32) {
    {
      const int m  = tid >> 2;
      const int kc = tid & 3;
      short8 v;
      const int grow = row0 + m;
      if (grow < N_NODES) {
        const float* src = x + (size_t)grow * D_IN + kt + kc * 8;
        const float4 f0 = *(const float4*)(src);
        const float4 f1 = *(const float4*)(src + 4);
        v[0] = f2bf(f0.x); v[1] = f2bf(f0.y); v[2] = f2bf(f0.z); v[3] = f2bf(f0.w);
        v[4] = f2bf(f1.x); v[5] = f2bf(f1.y); v[6] = f2bf(f1.z); v[7] = f2bf(f1.w);
      } else {
        v = (short8)0;
      }
      *(short8*)&As[m][kc * 8] = v;
    }
    {
#pragma unroll
      for (int c = 0; c < 2; ++c) {
        const int t2 = (tid << 1) | c;
        const int n  = t2 >> 2;
        const int kc = t2 & 3;
        const short8 v = *(const short8*)(W1t + (size_t)n * D_IN + kt + kc * 8);
        *(short8*)&Bs[n][kc * 8] = v;
      }
    }
    __syncthreads();

    short8 a[4], b[4];
#pragma unroll
    for (int mi = 0; mi < 4; ++mi)
      a[mi] = *(const short8*)&As[wm * 64 + mi * 16 + lr][lg * 8];
#pragma unroll
    for (int nj = 0; nj < 4; ++nj)
      b[nj] = *(const short8*)&Bs[wn * 64 + nj * 16 + lr][lg * 8];

#pragma unroll
    for (int mi = 0; mi < 4; ++mi)
#pragma unroll
      for (int nj = 0; nj < 4; ++nj)
        acc[mi][nj] = __builtin_amdgcn_mfma_f32_16x16x32_bf16(a[mi], b[nj], acc[mi][nj], 0, 0, 0);

    __syncthreads();
  }

#pragma unroll
  for (int mi = 0; mi < 4; ++mi) {
#pragma unroll
    for (int nj = 0; nj < 4; ++nj) {
      const int gcol = wn * 64 + nj * 16 + lr;
#pragma unroll
      for (int r = 0; r < 4; ++r) {
        const int grow = row0 + wm * 64 + mi * 16 + lg * 4 + r;
        if (grow < N_NODES) out[(size_t)grow * D_HID + gcol] = f2bf(acc[mi][nj][r]);
      }
    }
  }
}

// ---------------------------------------------------------------------------
// SpMM1 (CSR) + fused bias + ReLU + dropout; bf16 in/out, f32 accum.
// Wave = two 32-lane halves; half h walks edges beg+h, beg+h+2, ...
// ---------------------------------------------------------------------------
__global__ __launch_bounds__(256) void spmm1_csr_kernel(const short* __restrict__ sup,
                                                        const int* __restrict__ rowptr,
                                                        const int2* __restrict__ pairs,
                                                        const float* __restrict__ b1,
                                                        short* __restrict__ h) {
  const int node = blockIdx.x * 4 + (threadIdx.x >> 6);
  const int lane = threadIdx.x & 63;
  const int half = lane >> 5;
  const int hl   = lane & 31;
  if (node >= N_NODES) return;
  const int beg = rowptr[node];
  const int end = rowptr[node + 1];

  float acc[8] = {};

  int e = beg + half;
  for (; e + 6 < end; e += 8) {
    const int2 p0 = pairs[e];
    const int2 p1 = pairs[e + 2];
    const int2 p2 = pairs[e + 4];
    const int2 p3 = pairs[e + 6];
    const short8 v0 = *(const short8*)(sup + (size_t)p0.x * D_HID + hl * 8);
    const short8 v1 = *(const short8*)(sup + (size_t)p1.x * D_HID + hl * 8);
    const short8 v2 = *(const short8*)(sup + (size_t)p2.x * D_HID + hl * 8);
    const short8 v3 = *(const short8*)(sup + (size_t)p3.x * D_HID + hl * 8);
    const float w0 = __int_as_float(p0.y);
    const float w1 = __int_as_float(p1.y);
    const float w2 = __int_as_float(p2.y);
    const float w3 = __int_as_float(p3.y);
#pragma unroll
    for (int j = 0; j < 8; ++j) acc[j] += w0 * bf2f((unsigned short)v0[j]);
#pragma unroll
    for (int j = 0; j < 8; ++j) acc[j] += w1 * bf2f((unsigned short)v1[j]);
#pragma unroll
    for (int j = 0; j < 8; ++j) acc[j] += w2 * bf2f((unsigned short)v2[j]);
#pragma unroll
    for (int j = 0; j < 8; ++j) acc[j] += w3 * bf2f((unsigned short)v3[j]);
  }
  for (; e < end; e += 2) {
    const int2 p0 = pairs[e];
    const float w0 = __int_as_float(p0.y);
    const short8 v0 = *(const short8*)(sup + (size_t)p0.x * D_HID + hl * 8);
#pragma unroll
    for (int j = 0; j < 8; ++j) acc[j] += w0 * bf2f((unsigned short)v0[j]);
  }

#pragma unroll
  for (int j = 0; j < 8; ++j) acc[j] += __shfl_xor(acc[j], 32, 64);

  const int col = hl * 8 + half * 4;
  short4v r;
#pragma unroll
  for (int j = 0; j < 4; ++j) {
    float v = acc[half * 4 + j] + b1[col + j];
    v = v > 0.0f ? v : 0.0f;
    unsigned o0, o1;
    threefry_0_42(0u, (unsigned)node * D_HID + col + j, o0, o1);
    const unsigned word = o0 ^ o1;
    r[j] = (word >> 31) ? (short)0 : f2bf(v * 2.0f);
  }
  *(short4v*)(h + (size_t)node * D_HID + col) = r;
}

// ---------------------------------------------------------------------------
// GEMM2 (bf16 MFMA): support2(bf16, stride S2_LD)[100000] = h(bf16) @ W2
// ---------------------------------------------------------------------------
__global__ __launch_bounds__(256) void gemm2_mfma_kernel(const short* __restrict__ h,
                                                         const short* __restrict__ W2t,
                                                         short* __restrict__ out) {
  __shared__ __attribute__((aligned(16))) short As[128][40];
  __shared__ __attribute__((aligned(16))) short Bs[48][40];

  const int tid  = threadIdx.x;
  const int lane = tid & 63;
  const int wm   = tid >> 6;
  const int lr   = lane & 15;
  const int lg   = lane >> 4;
  const int row0 = blockIdx.x * 128;

  f32x4 acc[2][3] = {};

  for (int kt = 0; kt < D_HID; kt += 32) {
    {
#pragma unroll
      for (int c = 0; c < 2; ++c) {
        const int t2 = (tid << 1) | c;
        const int m  = t2 >> 2;
        const int kc = t2 & 3;
        const int grow = row0 + m;
        short8 v = (short8)0;
        if (grow < N_NODES)
          v = *(const short8*)(h + (size_t)grow * D_HID + kt + kc * 8);
        *(short8*)&As[m][kc * 8] = v;
      }
    }
    if (tid < 192) {
      const int n  = tid >> 2;
      const int kc = tid & 3;
      const short8 v = *(const short8*)(W2t + (size_t)n * D_HID + kt + kc * 8);
      *(short8*)&Bs[n][kc * 8] = v;
    }
    __syncthreads();

    short8 a[2], b[3];
#pragma unroll
    for (int mi = 0; mi < 2; ++mi)
      a[mi] = *(const short8*)&As[wm * 32 + mi * 16 + lr][lg * 8];
#pragma unroll
    for (int nj = 0; nj < 3; ++nj)
      b[nj] = *(const short8*)&Bs[nj * 16 + lr][lg * 8];

#pragma unroll
    for (int mi = 0; mi < 2; ++mi)
#pragma unroll
      for (int nj = 0; nj < 3; ++nj)
        acc[mi][nj] = __builtin_amdgcn_mfma_f32_16x16x32_bf16(a[mi], b[nj], acc[mi][nj], 0, 0, 0);

    __syncthreads();
  }

#pragma unroll
  for (int mi = 0; mi < 2; ++mi) {
#pragma unroll
    for (int nj = 0; nj < 3; ++nj) {
      const int gcol = nj * 16 + lr;
      if (gcol < D_OUT) {
#pragma unroll
        for (int r = 0; r < 4; ++r) {
          const int grow = row0 + wm * 32 + mi * 16 + lg * 4 + r;
          if (grow < N_NODES) out[(size_t)grow * S2_LD + gcol] = f2bf(acc[mi][nj][r]);
        }
      }
    }
  }
}

// ---------------------------------------------------------------------------
// SpMM2 (CSR, bf16, stride S2_LD) + fused bias + log_softmax -> d_out
// Two nodes per wave (one per 32-lane half), 2 feats/lane (uint = 2 bf16).
// ---------------------------------------------------------------------------
__global__ __launch_bounds__(256) void spmm2_csr_kernel(const short* __restrict__ sup2,
                                                        const int* __restrict__ rowptr,
                                                        const int2* __restrict__ pairs,
                                                        const float* __restrict__ b2,
                                                        float* __restrict__ out) {
  const int lane = threadIdx.x & 63;
  const int half = lane >> 5;
  const int hl   = lane & 31;
  const int node = blockIdx.x * 8 + ((threadIdx.x >> 6) << 1) + half;
  if (node >= N_NODES) return;
  const int beg = rowptr[node];
  const int end = rowptr[node + 1];
  const bool act = hl < 20;

  float a0 = 0.f, a1 = 0.f, b0 = 0.f, b1 = 0.f;
  float c0 = 0.f, c1 = 0.f, d0 = 0.f, d1 = 0.f;
  int e = beg;
  for (; e + 4 <= end; e += 4) {
    const int2 p0 = pairs[e], p1 = pairs[e + 1], p2 = pairs[e + 2], p3 = pairs[e + 3];
    if (act) {
      const unsigned u0 = *(const unsigned*)(sup2 + (size_t)p0.x * S2_LD + hl * 2);
      const unsigned u1 = *(const unsigned*)(sup2 + (size_t)p1.x * S2_LD + hl * 2);
      const unsigned u2 = *(const unsigned*)(sup2 + (size_t)p2.x * S2_LD + hl * 2);
      const unsigned u3 = *(const unsigned*)(sup2 + (size_t)p3.x * S2_LD + hl * 2);
      const float w0 = __int_as_float(p0.y);
      const float w1 = __int_as_float(p1.y);
      const float w2 = __int_as_float(p2.y);
      const float w3 = __int_as_float(p3.y);
      a0 += w0 * bf2f((unsigned short)(u0 & 0xffff)); a1 += w0 * bf2f((unsigned short)(u0 >> 16));
      b0 += w1 * bf2f((unsigned short)(u1 & 0xffff)); b1 += w1 * bf2f((unsigned short)(u1 >> 16));
      c0 += w2 * bf2f((unsigned short)(u2 & 0xffff)); c1 += w2 * bf2f((unsigned short)(u2 >> 16));
      d0 += w3 * bf2f((unsigned short)(u3 & 0xffff)); d1 += w3 * bf2f((unsigned short)(u3 >> 16));
    }
  }
  for (; e < end; ++e) {
    const int2 p0 = pairs[e];
    if (act) {
      const unsigned u0 = *(const unsigned*)(sup2 + (size_t)p0.x * S2_LD + hl * 2);
      const float w0 = __int_as_float(p0.y);
      a0 += w0 * bf2f((unsigned short)(u0 & 0xffff)); a1 += w0 * bf2f((unsigned short)(u0 >> 16));
    }
  }
  const float f0 = (a0 + b0) + (c0 + d0);
  const float f1 = (a1 + b1) + (c1 + d1);

  const float v0 = act ? f0 + b2[hl * 2]     : -INFINITY;
  const float v1 = act ? f1 + b2[hl * 2 + 1] : -INFINITY;
  float m = fmaxf(v0, v1);
#pragma unroll
  for (int off = 16; off > 0; off >>= 1) m = fmaxf(m, __shfl_xor(m, off, 32));
  float s = act ? __expf(v0 - m) + __expf(v1 - m) : 0.0f;
#pragma unroll
  for (int off = 16; off > 0; off >>= 1) s += __shfl_xor(s, off, 32);
  if (act) {
    const float ls = logf(s);
    float2 r;
    r.x = v0 - m - ls;
    r.y = v1 - m - ls;
    *(float2*)&out[(size_t)node * D_OUT + hl * 2] = r;
  }
}

// ---------------------------------------------------------------------------
extern "C" void kernel_launch(void* const* d_in, const int* in_sizes, int n_in,
                              void* d_out, int out_size, void* d_ws, size_t ws_size,
                              hipStream_t stream) {
  const float* x    = (const float*)d_in[0];
  const int*   esrc = (const int*)d_in[1];
  const int*   edst = (const int*)d_in[2];
  const float* ew   = (const float*)d_in[3];
  const float* W1   = (const float*)d_in[4];
  const float* b1   = (const float*)d_in[5];
  const float* W2   = (const float*)d_in[6];
  const float* b2   = (const float*)d_in[7];
  float* out = (float*)d_out;

  float* ws = (float*)d_ws;
  short* support1 = (short*)ws;                  // 25,600,000 bf16 (51.2 MB)
  short* hbuf     = (short*)(ws + 12800000);     // 25,600,000 bf16 (51.2 MB)
  short* support2 = (short*)(ws + 25600000);     //  4,800,000 bf16 (9.6 MB, stride 48)
  int2*  pairs    = (int2*)(ws + 30400000);      //  1,600,000 int2 (12.8 MB)
  int*   rowptr   = (int*)(ws + 33600000);       //    100,001 i
  int*   counts   = (int*)(ws + 33700008);       //    100,000 i
  int*   cursor   = (int*)(ws + 33800008);       //    100,000 i
  short* W1t      = (short*)(ws + 33900008);     //    131,072 bf16
  short* W2t      = (short*)(ws + 33965544);     //     12,288 bf16
  int*   bsums    = (int*)(ws + 33971688);       //        391 i
  int*   boffs    = bsums + 512;                 //        391 i

  hipMemsetAsync(counts, 0, N_NODES * sizeof(int), stream);

  // K1: gemm1 + hist + wprep in one grid.
  // NOTE: gemm1 consumes W1t written by the wprep blocks of the SAME launch —
  // that would be a race, so gemm1 reads W1t only if it was produced earlier.
  // To keep it safe, wprep must complete BEFORE gemm1 blocks read W1t.
  // We guarantee this by running wprep in a separate prior launch is gone —
  // instead gemm1's B-operand is read from W1t produced here: blocks are not
  // ordered, so gemm1 stages B directly from W1 (f32) would be needed.
  // SAFE RESOLUTION: wprep here only writes W2t (needed later by gemm2);
  // W1t is produced by a tiny dedicated launch BEFORE K1.
  {
    // tiny W1t-only prep (0.13M elements, ~3 µs)
    // reuse scan_apply-style simple kernel via lambda-free dispatch below
  }
  // W1t prep (dedicated, must precede K1's gemm1 blocks)
  {
    struct L { static __global__ void w1t(const float* W1, short* W1t) {
    } };
  }

  // --- launches ---
  // 1) W1t prep (dedicated)
  extern __global__ void w1t_only_kernel(const float*, short*);
  w1t_only_kernel<<<(D_IN * D_HID + 511) / 512, 512, 0, stream>>>(W1, W1t);

  // 2) merged gemm1 + hist + W2t-prep
  k1_gemm1_hist_wprep_kernel<<<G1_BLOCKS + HIST_BLOCKS + WPREP_BLOCKS, 512, 0, stream>>>(
      x, W1t, support1, edst, counts, W1, W2, W1t, W2t);

  // 3) CSR scan + scatter
  block_sum_kernel<<<SCAN_BLOCKS, 256, 0, stream>>>(counts, bsums);
  bsum_scan_kernel<<<1, 512, 0, stream>>>(bsums, boffs);
  scan_apply_kernel<<<SCAN_BLOCKS, 256, 0, stream>>>(counts, boffs, rowptr, cursor);
  scatter_kernel<<<(N_EDGES + 255) / 256, 256, 0, stream>>>(esrc, edst, ew, cursor, pairs);

  // layer 1 aggregation
  spmm1_csr_kernel<<<(N_NODES + 3) / 4, 256, 0, stream>>>(support1, rowptr, pairs, b1, hbuf);

  // layer 2
  gemm2_mfma_kernel<<<(N_NODES + 127) / 128, 256, 0, stream>>>(hbuf, W2t, support2);
  spmm2_csr_kernel<<<(N_NODES + 7) / 8, 256, 0, stream>>>(support2, rowptr, pairs, b2, out);
}

// dedicated W1t prep: W1 [512][256] f32 -> W1t [256][512] bf16
__global__ __launch_bounds__(512) void w1t_only_kernel(const float* __restrict__ W1,
                                                       short* __restrict__ W1t) {
  const int i = blockIdx.x * 512 + threadIdx.x;
  if (i >= D_IN * D_HID) return;
  const int n = i >> 9;
  const int k = i & 511;
  W1t[i] = f2bf(W1[(size_t)k * D_HID + n]);
}